// Round 1
// baseline (414.373 us; speedup 1.0000x reference)
//
#include <hip/hip_runtime.h>

#define NBATCH 4096
#define NNODE  32
#define NVOCAB 100
#define DIM    64
#define EPG    512
#define HSTR   68      // padded LDS row stride (floats): 16B-aligned rows, bank-staggered
#define LN_EPS 1e-5f

__device__ __forceinline__ float4 ldg4(const float* __restrict__ p) {
    return *reinterpret_cast<const float4*>(p);
}

extern "C" __global__ void __launch_bounds__(256)
gin_fused_kernel(const int* __restrict__ x, const int* __restrict__ los,
                 const int* __restrict__ eidx, const float* __restrict__ emb,
                 const float* __restrict__ win1, const float* __restrict__ bin1,
                 const float* __restrict__ gin_g, const float* __restrict__ gin_b,
                 const float* __restrict__ win2, const float* __restrict__ bin2,
                 const float* __restrict__ wh1, const float* __restrict__ bh1,
                 const float* __restrict__ gh_g, const float* __restrict__ gh_b,
                 const float* __restrict__ wh2, const float* __restrict__ bh2,
                 const float* __restrict__ epsv,
                 const float* __restrict__ wc1, const float* __restrict__ bc1,
                 const float* __restrict__ wc2, const float* __restrict__ bc2,
                 float* __restrict__ out)
{
    __shared__ __align__(16) float bufA[NNODE * HSTR];
    __shared__ __align__(16) float bufB[NNODE * HSTR];
    __shared__ int   srt[EPG];          // sorted-by-dst src offsets (premultiplied by HSTR)
    __shared__ int   estart[NNODE + 1]; // CSR-style offsets per dst node
    __shared__ int   ecur[NNODE];
    __shared__ float pooled[3 * DIM];
    __shared__ float red[4];

    const int b = blockIdx.x;
    const int t = threadIdx.x;

    if (t < NNODE) ecur[t] = 0;
    __syncthreads();

    // ---- load this graph's 512 edges into registers + histogram by dst ----
    const int ebase = b * EPG;
    const int goff  = b * NNODE;
    const int s0 = eidx[ebase + t] - goff;
    const int d0 = eidx[NBATCH * EPG + ebase + t] - goff;
    const int s1 = eidx[ebase + 256 + t] - goff;
    const int d1 = eidx[NBATCH * EPG + ebase + 256 + t] - goff;
    atomicAdd(&ecur[d0], 1);
    atomicAdd(&ecur[d1], 1);

    // ---- embedding lookup -> bufA  (h[n][d] = emb[n, xf[b,n], d]) ----
    for (int i = t; i < NNODE * 16; i += 256) {
        const int n = i >> 4, q = i & 15;
        const int idx = (n < (NNODE - 1)) ? x[b * (NNODE - 1) + n] : los[b];
        const float4 v = ldg4(emb + ((size_t)(n * NVOCAB + idx)) * DIM + q * 4);
        *reinterpret_cast<float4*>(&bufA[n * HSTR + q * 4]) = v;
    }
    __syncthreads();

    // ---- prefix sum (counting sort, built once, reused for 3 layers) ----
    if (t == 0) {
        int acc = 0;
        for (int n = 0; n < NNODE; ++n) {
            const int c = ecur[n];
            estart[n] = acc;
            ecur[n]   = acc;
            acc += c;
        }
        estart[NNODE] = acc;
    }
    __syncthreads();

    {
        const int p0 = atomicAdd(&ecur[d0], 1); srt[p0] = s0 * HSTR;
        const int p1 = atomicAdd(&ecur[d1], 1); srt[p1] = s1 * HSTR;
    }
    __syncthreads();

    float* hin  = bufA;
    float* zbuf = bufB;
    const int lane16 = t & 15;
    const int grp    = t >> 4;
    const int row    = t >> 3;
    const int cg     = t & 7;
    const int cbase  = cg * 8;

    for (int l = 0; l < 3; ++l) {
        const float* W1 = (l == 0) ? win1  : wh1;
        const float* B1 = (l == 0) ? bin1  : bh1;
        const float* Gg = (l == 0) ? gin_g : gh_g;
        const float* Gb = (l == 0) ? gin_b : gh_b;
        const float* W2 = (l == 0) ? win2  : wh2;
        const float* B2 = (l == 0) ? bin2  : bh2;
        const float  sc = 1.0f + epsv[l];

        // ---- gather: z[n] = (1+eps)*h[n] + sum_{src->n} h[src] ----
        for (int half = 0; half < 2; ++half) {
            const int n = grp + half * 16;
            const int o = lane16 * 4;
            const float4 hs = *reinterpret_cast<const float4*>(&hin[n * HSTR + o]);
            float ax = sc * hs.x, ay = sc * hs.y, az = sc * hs.z, aw = sc * hs.w;
            const int je = estart[n + 1];
            for (int j = estart[n]; j < je; ++j) {
                const int so = srt[j];
                const float4 hv = *reinterpret_cast<const float4*>(&hin[so + o]);
                ax += hv.x; ay += hv.y; az += hv.z; aw += hv.w;
            }
            float4 r; r.x = ax; r.y = ay; r.z = az; r.w = aw;
            *reinterpret_cast<float4*>(&zbuf[n * HSTR + o]) = r;
        }
        __syncthreads();

        // ---- matmul1 (z @ W1 + b1) + LayerNorm + relu -> hin ----
        float acc[8];
        #pragma unroll
        for (int j2 = 0; j2 < 8; ++j2) acc[j2] = 0.f;
        for (int k0 = 0; k0 < 16; ++k0) {
            const float4 zv = *reinterpret_cast<const float4*>(&zbuf[row * HSTR + k0 * 4]);
            const float zz[4] = { zv.x, zv.y, zv.z, zv.w };
            #pragma unroll
            for (int kk = 0; kk < 4; ++kk) {
                const int k = k0 * 4 + kk;
                const float4 w0 = ldg4(W1 + k * DIM + cbase);
                const float4 w1 = ldg4(W1 + k * DIM + cbase + 4);
                const float zs = zz[kk];
                acc[0] = fmaf(zs, w0.x, acc[0]);
                acc[1] = fmaf(zs, w0.y, acc[1]);
                acc[2] = fmaf(zs, w0.z, acc[2]);
                acc[3] = fmaf(zs, w0.w, acc[3]);
                acc[4] = fmaf(zs, w1.x, acc[4]);
                acc[5] = fmaf(zs, w1.y, acc[5]);
                acc[6] = fmaf(zs, w1.z, acc[6]);
                acc[7] = fmaf(zs, w1.w, acc[7]);
            }
        }
        float sum1 = 0.f, sum2 = 0.f;
        #pragma unroll
        for (int j2 = 0; j2 < 8; ++j2) {
            const float v = acc[j2] + B1[cbase + j2];
            acc[j2] = v;
            sum1 += v;
            sum2 += v * v;
        }
        // LN stats across the 8 lanes that share this row (lanes row*8 .. row*8+7)
        sum1 += __shfl_xor(sum1, 1); sum1 += __shfl_xor(sum1, 2); sum1 += __shfl_xor(sum1, 4);
        sum2 += __shfl_xor(sum2, 1); sum2 += __shfl_xor(sum2, 2); sum2 += __shfl_xor(sum2, 4);
        const float mu  = sum1 * (1.0f / 64.0f);
        const float var = sum2 * (1.0f / 64.0f) - mu * mu;
        const float inv = rsqrtf(var + LN_EPS);
        #pragma unroll
        for (int j2 = 0; j2 < 8; ++j2) {
            const float yv = (acc[j2] - mu) * inv * Gg[cbase + j2] + Gb[cbase + j2];
            acc[j2] = fmaxf(yv, 0.f);
        }
        {
            float4 v0; v0.x = acc[0]; v0.y = acc[1]; v0.z = acc[2]; v0.w = acc[3];
            float4 v1; v1.x = acc[4]; v1.y = acc[5]; v1.z = acc[6]; v1.w = acc[7];
            *reinterpret_cast<float4*>(&hin[row * HSTR + cbase])     = v0;
            *reinterpret_cast<float4*>(&hin[row * HSTR + cbase + 4]) = v1;
        }
        __syncthreads();

        // ---- matmul2 (y @ W2 + b2) -> zbuf ----
        float acc2[8];
        #pragma unroll
        for (int j2 = 0; j2 < 8; ++j2) acc2[j2] = 0.f;
        for (int k0 = 0; k0 < 16; ++k0) {
            const float4 zv = *reinterpret_cast<const float4*>(&hin[row * HSTR + k0 * 4]);
            const float zz[4] = { zv.x, zv.y, zv.z, zv.w };
            #pragma unroll
            for (int kk = 0; kk < 4; ++kk) {
                const int k = k0 * 4 + kk;
                const float4 w0 = ldg4(W2 + k * DIM + cbase);
                const float4 w1 = ldg4(W2 + k * DIM + cbase + 4);
                const float zs = zz[kk];
                acc2[0] = fmaf(zs, w0.x, acc2[0]);
                acc2[1] = fmaf(zs, w0.y, acc2[1]);
                acc2[2] = fmaf(zs, w0.z, acc2[2]);
                acc2[3] = fmaf(zs, w0.w, acc2[3]);
                acc2[4] = fmaf(zs, w1.x, acc2[4]);
                acc2[5] = fmaf(zs, w1.y, acc2[5]);
                acc2[6] = fmaf(zs, w1.z, acc2[6]);
                acc2[7] = fmaf(zs, w1.w, acc2[7]);
            }
        }
        #pragma unroll
        for (int j2 = 0; j2 < 8; ++j2) acc2[j2] += B2[cbase + j2];
        {
            float4 v0; v0.x = acc2[0]; v0.y = acc2[1]; v0.z = acc2[2]; v0.w = acc2[3];
            float4 v1; v1.x = acc2[4]; v1.y = acc2[5]; v1.z = acc2[6]; v1.w = acc2[7];
            *reinterpret_cast<float4*>(&zbuf[row * HSTR + cbase])     = v0;
            *reinterpret_cast<float4*>(&zbuf[row * HSTR + cbase + 4]) = v1;
        }
        __syncthreads();

        // ---- pooled[l][d] = sum over nodes of layer output ----
        if (t < DIM) {
            float s = 0.f;
            #pragma unroll
            for (int n = 0; n < NNODE; ++n) s += zbuf[n * HSTR + t];
            pooled[l * DIM + t] = s;
        }
        // ping-pong: layer output becomes next layer's input
        float* tswap = hin; hin = zbuf; zbuf = tswap;
    }
    __syncthreads();

    // ---- classifier: relu(pooled @ wc1 + bc1) @ wc2 + bc2 ----
    float partial = 0.f;
    for (int j = t; j < 2 * 3 * DIM; j += 256) {
        float a = bc1[j];
        for (int i = 0; i < 3 * DIM; ++i) a = fmaf(pooled[i], wc1[i * 384 + j], a);
        partial += fmaxf(a, 0.f) * wc2[j];
    }
    partial += __shfl_xor(partial, 1);
    partial += __shfl_xor(partial, 2);
    partial += __shfl_xor(partial, 4);
    partial += __shfl_xor(partial, 8);
    partial += __shfl_xor(partial, 16);
    partial += __shfl_xor(partial, 32);
    if ((t & 63) == 0) red[t >> 6] = partial;
    __syncthreads();
    if (t == 0) out[b] = red[0] + red[1] + red[2] + red[3] + bc2[0];
}

extern "C" void kernel_launch(void* const* d_in, const int* in_sizes, int n_in,
                              void* d_out, int out_size, void* d_ws, size_t ws_size,
                              hipStream_t stream)
{
    const int*   x     = (const int*)d_in[0];
    const int*   los   = (const int*)d_in[1];
    const int*   eidx  = (const int*)d_in[2];
    const float* emb   = (const float*)d_in[3];
    const float* win1  = (const float*)d_in[4];
    const float* bin1  = (const float*)d_in[5];
    const float* gin_g = (const float*)d_in[6];
    const float* gin_b = (const float*)d_in[7];
    const float* win2  = (const float*)d_in[8];
    const float* bin2  = (const float*)d_in[9];
    const float* wh1   = (const float*)d_in[10];
    const float* bh1   = (const float*)d_in[11];
    const float* gh_g  = (const float*)d_in[12];
    const float* gh_b  = (const float*)d_in[13];
    const float* wh2   = (const float*)d_in[14];
    const float* bh2   = (const float*)d_in[15];
    const float* epsv  = (const float*)d_in[16];
    const float* wc1   = (const float*)d_in[17];
    const float* bc1   = (const float*)d_in[18];
    const float* wc2   = (const float*)d_in[19];
    const float* bc2   = (const float*)d_in[20];
    float* out = (float*)d_out;

    hipLaunchKernelGGL(gin_fused_kernel, dim3(NBATCH), dim3(256), 0, stream,
                       x, los, eidx, emb, win1, bin1, gin_g, gin_b, win2, bin2,
                       wh1, bh1, gh_g, gh_b, wh2, bh2, epsv, wc1, bc1, wc2, bc2, out);
}

// Round 2
// 177.736 us; speedup vs baseline: 2.3314x; 2.3314x over previous
//
#include <hip/hip_runtime.h>

#define NBATCH 4096
#define NNODE  32
#define NVOCAB 100
#define DIM    64
#define EPG    512
#define HSTR   68      // padded fp32 LDS row stride
#define LN_EPS 1e-5f

typedef float          f32x4  __attribute__((ext_vector_type(4)));
typedef unsigned int   u32x4  __attribute__((ext_vector_type(4)));
typedef __bf16         bf16x8 __attribute__((ext_vector_type(8)));

__device__ __forceinline__ float4 ldg4(const float* __restrict__ p) {
    return *reinterpret_cast<const float4*>(p);
}
__device__ __forceinline__ unsigned short f2bf(float f) {
    unsigned int u = __builtin_bit_cast(unsigned int, f);
    u += 0x7fffu + ((u >> 16) & 1u);            // round-to-nearest-even
    return (unsigned short)(u >> 16);
}
__device__ __forceinline__ float bf2f(unsigned short h) {
    unsigned int u = ((unsigned int)h) << 16;
    return __builtin_bit_cast(float, u);
}
__device__ __forceinline__ bf16x8 as_bf(u32x4 v) {
    return __builtin_bit_cast(bf16x8, v);
}

// ---- pre-kernel: split W into bf16 hi/lo and pack into MFMA B-fragment order ----
// fragment f = (s*4 + n)*64 + l  holds W[k = s*32 + (l>>4)*8 + j][col = n*16 + (l&15)], j=0..7
// per matrix: 4096 hi bf16 + 4096 lo bf16 = 16 KB. matrices: win1, win2, wh1, wh2.
extern "C" __global__ void __launch_bounds__(256)
prep_w_kernel(const float* __restrict__ win1, const float* __restrict__ win2,
              const float* __restrict__ wh1,  const float* __restrict__ wh2,
              unsigned short* __restrict__ wsb)
{
    const float* Ws[4] = {win1, win2, wh1, wh2};
    const float* W = Ws[blockIdx.x];
    unsigned short* hi = wsb + blockIdx.x * 8192;
    unsigned short* lo = hi + 4096;
    for (int f = threadIdx.x; f < 512; f += 256) {
        const int s = f >> 8, n = (f >> 6) & 3, l = f & 63;
        const int g = l >> 4, c = l & 15, col = n * 16 + c;
        unsigned int uh[4], ul[4];
        #pragma unroll
        for (int j2 = 0; j2 < 4; ++j2) {
            unsigned short h2[2], l2[2];
            #pragma unroll
            for (int e = 0; e < 2; ++e) {
                const int j = j2 * 2 + e;
                const float v = W[(s * 32 + g * 8 + j) * DIM + col];
                h2[e] = f2bf(v);
                l2[e] = f2bf(v - bf2f(h2[e]));
            }
            uh[j2] = (unsigned int)h2[0] | ((unsigned int)h2[1] << 16);
            ul[j2] = (unsigned int)l2[0] | ((unsigned int)l2[1] << 16);
        }
        *(u32x4*)(hi + f * 8) = (u32x4){uh[0], uh[1], uh[2], uh[3]};
        *(u32x4*)(lo + f * 8) = (u32x4){ul[0], ul[1], ul[2], ul[3]};
    }
}

// ---- MFMA core: D(32x64) = Z(32x64) @ W(64x64), bf16x2-split, fp32 accum ----
// wave w = t>>6: m = w&1 (row tile), npair = w>>1 (col tiles 2*npair, 2*npair+1)
__device__ __forceinline__ void mfma_mm(const unsigned int* __restrict__ zh,
                                        const unsigned int* __restrict__ zl,
                                        const unsigned short* __restrict__ wf,
                                        int m, int npair, int l,
                                        f32x4& acc0, f32x4& acc1)
{
    const u32x4 ah0 = *(const u32x4*)&zh[((0 * 2 + m) * 64 + l) * 4];
    const u32x4 ah1 = *(const u32x4*)&zh[((1 * 2 + m) * 64 + l) * 4];
    const u32x4 al0 = *(const u32x4*)&zl[((0 * 2 + m) * 64 + l) * 4];
    const u32x4 al1 = *(const u32x4*)&zl[((1 * 2 + m) * 64 + l) * 4];
    const unsigned short* wlo = wf + 4096;
    #pragma unroll
    for (int nn = 0; nn < 2; ++nn) {
        const int n = npair * 2 + nn;
        const u32x4 bh0 = *(const u32x4*)&wf [((0 * 4 + n) * 64 + l) * 8];
        const u32x4 bh1 = *(const u32x4*)&wf [((1 * 4 + n) * 64 + l) * 8];
        const u32x4 bl0 = *(const u32x4*)&wlo[((0 * 4 + n) * 64 + l) * 8];
        const u32x4 bl1 = *(const u32x4*)&wlo[((1 * 4 + n) * 64 + l) * 8];
        f32x4& acc = nn ? acc1 : acc0;
        acc = __builtin_amdgcn_mfma_f32_16x16x32_bf16(as_bf(ah0), as_bf(bh0), acc, 0, 0, 0);
        acc = __builtin_amdgcn_mfma_f32_16x16x32_bf16(as_bf(ah0), as_bf(bl0), acc, 0, 0, 0);
        acc = __builtin_amdgcn_mfma_f32_16x16x32_bf16(as_bf(al0), as_bf(bh0), acc, 0, 0, 0);
        acc = __builtin_amdgcn_mfma_f32_16x16x32_bf16(as_bf(ah1), as_bf(bh1), acc, 0, 0, 0);
        acc = __builtin_amdgcn_mfma_f32_16x16x32_bf16(as_bf(ah1), as_bf(bl1), acc, 0, 0, 0);
        acc = __builtin_amdgcn_mfma_f32_16x16x32_bf16(as_bf(al1), as_bf(bh1), acc, 0, 0, 0);
    }
}

extern "C" __global__ void __launch_bounds__(256)
gin_fused_kernel(const int* __restrict__ x, const int* __restrict__ los,
                 const int* __restrict__ eidx, const float* __restrict__ emb,
                 const float* __restrict__ bin1,
                 const float* __restrict__ gin_g, const float* __restrict__ gin_b,
                 const float* __restrict__ bin2,
                 const float* __restrict__ bh1,
                 const float* __restrict__ gh_g, const float* __restrict__ gh_b,
                 const float* __restrict__ bh2,
                 const float* __restrict__ epsv,
                 const float* __restrict__ wc1, const float* __restrict__ bc1,
                 const float* __restrict__ wc2, const float* __restrict__ bc2,
                 const unsigned short* __restrict__ wsb,
                 float* __restrict__ out)
{
    __shared__ __align__(16) float Hf[NNODE * HSTR];      // fp32 node features / matmul out
    __shared__ __align__(16) unsigned int zh_f[1024];     // bf16-hi fragments (2s x 2m x 64l x 16B)
    __shared__ __align__(16) unsigned int zl_f[1024];     // bf16-lo fragments
    __shared__ int   srt[EPG];
    __shared__ int   estart[NNODE + 1];
    __shared__ int   ecur[NNODE];
    __shared__ float pooled[3 * DIM];
    __shared__ float red[4];

    const int b = blockIdx.x;
    const int t = threadIdx.x;

    if (t < NNODE) ecur[t] = 0;
    __syncthreads();

    // ---- edges: histogram by dst ----
    const int ebase = b * EPG;
    const int goff  = b * NNODE;
    const int s0 = eidx[ebase + t] - goff;
    const int d0 = eidx[NBATCH * EPG + ebase + t] - goff;
    const int s1 = eidx[ebase + 256 + t] - goff;
    const int d1 = eidx[NBATCH * EPG + ebase + 256 + t] - goff;
    atomicAdd(&ecur[d0], 1);
    atomicAdd(&ecur[d1], 1);

    // ---- embedding lookup -> Hf ----
    for (int i = t; i < NNODE * 16; i += 256) {
        const int n = i >> 4, q = i & 15;
        const int idx = (n < (NNODE - 1)) ? x[b * (NNODE - 1) + n] : los[b];
        const float4 v = ldg4(emb + ((size_t)(n * NVOCAB + idx)) * DIM + q * 4);
        *reinterpret_cast<float4*>(&Hf[n * HSTR + q * 4]) = v;
    }
    __syncthreads();

    // ---- prefix + counting-sort scatter (built once, reused 3 layers) ----
    if (t == 0) {
        int acc = 0;
        for (int n = 0; n < NNODE; ++n) {
            const int c = ecur[n];
            estart[n] = acc; ecur[n] = acc; acc += c;
        }
        estart[NNODE] = acc;
    }
    __syncthreads();
    {
        const int p0 = atomicAdd(&ecur[d0], 1); srt[p0] = s0 * HSTR;
        const int p1 = atomicAdd(&ecur[d1], 1); srt[p1] = s1 * HSTR;
    }
    __syncthreads();

    const int lane16 = t & 15;
    const int grp    = t >> 4;
    const int row    = t >> 3;
    const int cg     = t & 7;
    const int cbase  = cg * 8;
    const int l64    = t & 63;
    const int wv     = t >> 6;
    const int mtile  = wv & 1;
    const int npair  = wv >> 1;

    for (int l = 0; l < 3; ++l) {
        const float* B1 = (l == 0) ? bin1  : bh1;
        const float* Gg = (l == 0) ? gin_g : gh_g;
        const float* Gb = (l == 0) ? gin_b : gh_b;
        const float* B2 = (l == 0) ? bin2  : bh2;
        const unsigned short* W1f = wsb + (l == 0 ? 0 : 2) * 8192;
        const unsigned short* W2f = wsb + (l == 0 ? 1 : 3) * 8192;
        const float sc = 1.0f + epsv[l];

        // ---- gather: z[n] = (1+eps)*h[n] + sum h[src]; split to bf16 hi/lo frags ----
        for (int half = 0; half < 2; ++half) {
            const int n = grp + half * 16;
            const int o = lane16 * 4;
            const float4 hs = *reinterpret_cast<const float4*>(&Hf[n * HSTR + o]);
            float zv[4] = { sc * hs.x, sc * hs.y, sc * hs.z, sc * hs.w };
            const int je = estart[n + 1];
            for (int j = estart[n]; j < je; ++j) {
                const int so = srt[j];
                const float4 hv = *reinterpret_cast<const float4*>(&Hf[so + o]);
                zv[0] += hv.x; zv[1] += hv.y; zv[2] += hv.z; zv[3] += hv.w;
            }
            // fragment position for (row=n, k=o..o+3)
            const int fi = ((o >> 5) * 2 + (n >> 4)) * 64 + ((o >> 3) & 3) * 16 + (n & 15);
            const int ui = fi * 4 + ((o & 4) >> 1);
            unsigned short h0 = f2bf(zv[0]), h1 = f2bf(zv[1]), h2 = f2bf(zv[2]), h3 = f2bf(zv[3]);
            uint2 wh_, wl_;
            wh_.x = (unsigned int)h0 | ((unsigned int)h1 << 16);
            wh_.y = (unsigned int)h2 | ((unsigned int)h3 << 16);
            unsigned short q0 = f2bf(zv[0] - bf2f(h0)), q1 = f2bf(zv[1] - bf2f(h1));
            unsigned short q2 = f2bf(zv[2] - bf2f(h2)), q3 = f2bf(zv[3] - bf2f(h3));
            wl_.x = (unsigned int)q0 | ((unsigned int)q1 << 16);
            wl_.y = (unsigned int)q2 | ((unsigned int)q3 << 16);
            *reinterpret_cast<uint2*>(&zh_f[ui]) = wh_;
            *reinterpret_cast<uint2*>(&zl_f[ui]) = wl_;
        }
        __syncthreads();

        // ---- matmul1 via MFMA -> Hf (fp32, +bias) ----
        {
            f32x4 acc0 = {0.f, 0.f, 0.f, 0.f}, acc1 = {0.f, 0.f, 0.f, 0.f};
            mfma_mm(zh_f, zl_f, W1f, mtile, npair, l64, acc0, acc1);
            const int cc = l64 & 15;
            const int rbase = mtile * 16 + (l64 >> 4) * 4;
            const int c0 = npair * 32 + cc;
            const int c1 = npair * 32 + 16 + cc;
            const float bb0 = B1[c0], bb1 = B1[c1];
            #pragma unroll
            for (int r = 0; r < 4; ++r) {
                Hf[(rbase + r) * HSTR + c0] = acc0[r] + bb0;
                Hf[(rbase + r) * HSTR + c1] = acc1[r] + bb1;
            }
        }
        __syncthreads();

        // ---- LayerNorm + relu -> bf16 hi/lo frags (y for matmul2) ----
        {
            const float4 v0 = *reinterpret_cast<const float4*>(&Hf[row * HSTR + cbase]);
            const float4 v1 = *reinterpret_cast<const float4*>(&Hf[row * HSTR + cbase + 4]);
            float y[8] = { v0.x, v0.y, v0.z, v0.w, v1.x, v1.y, v1.z, v1.w };
            float sum1 = 0.f, sum2 = 0.f;
            #pragma unroll
            for (int j = 0; j < 8; ++j) { sum1 += y[j]; sum2 += y[j] * y[j]; }
            sum1 += __shfl_xor(sum1, 1); sum1 += __shfl_xor(sum1, 2); sum1 += __shfl_xor(sum1, 4);
            sum2 += __shfl_xor(sum2, 1); sum2 += __shfl_xor(sum2, 2); sum2 += __shfl_xor(sum2, 4);
            const float mu  = sum1 * (1.0f / 64.0f);
            const float var = sum2 * (1.0f / 64.0f) - mu * mu;
            const float inv = rsqrtf(var + LN_EPS);
            const float4 gg0 = ldg4(Gg + cbase), gg1 = ldg4(Gg + cbase + 4);
            const float4 gb0 = ldg4(Gb + cbase), gb1 = ldg4(Gb + cbase + 4);
            const float ggs[8] = { gg0.x, gg0.y, gg0.z, gg0.w, gg1.x, gg1.y, gg1.z, gg1.w };
            const float gbs[8] = { gb0.x, gb0.y, gb0.z, gb0.w, gb1.x, gb1.y, gb1.z, gb1.w };
            unsigned int uh[4], ul[4];
            #pragma unroll
            for (int j2 = 0; j2 < 4; ++j2) {
                unsigned short hh[2], ll[2];
                #pragma unroll
                for (int e = 0; e < 2; ++e) {
                    const int j = j2 * 2 + e;
                    const float v = fmaxf((y[j] - mu) * inv * ggs[j] + gbs[j], 0.f);
                    hh[e] = f2bf(v);
                    ll[e] = f2bf(v - bf2f(hh[e]));
                }
                uh[j2] = (unsigned int)hh[0] | ((unsigned int)hh[1] << 16);
                ul[j2] = (unsigned int)ll[0] | ((unsigned int)ll[1] << 16);
            }
            const int s_ = cg >> 2, g_ = cg & 3, m_ = row >> 4, c_ = row & 15;
            const int fi = (s_ * 2 + m_) * 64 + g_ * 16 + c_;
            *reinterpret_cast<u32x4*>(&zh_f[fi * 4]) = (u32x4){uh[0], uh[1], uh[2], uh[3]};
            *reinterpret_cast<u32x4*>(&zl_f[fi * 4]) = (u32x4){ul[0], ul[1], ul[2], ul[3]};
        }
        __syncthreads();

        // ---- matmul2 via MFMA -> Hf (fp32, +bias) = layer output / next h ----
        {
            f32x4 acc0 = {0.f, 0.f, 0.f, 0.f}, acc1 = {0.f, 0.f, 0.f, 0.f};
            mfma_mm(zh_f, zl_f, W2f, mtile, npair, l64, acc0, acc1);
            const int cc = l64 & 15;
            const int rbase = mtile * 16 + (l64 >> 4) * 4;
            const int c0 = npair * 32 + cc;
            const int c1 = npair * 32 + 16 + cc;
            const float bb0 = B2[c0], bb1 = B2[c1];
            #pragma unroll
            for (int r = 0; r < 4; ++r) {
                Hf[(rbase + r) * HSTR + c0] = acc0[r] + bb0;
                Hf[(rbase + r) * HSTR + c1] = acc1[r] + bb1;
            }
        }
        __syncthreads();

        // ---- pooled[l][d] = sum over nodes ----
        if (t < DIM) {
            float s = 0.f;
            #pragma unroll
            for (int n = 0; n < NNODE; ++n) s += Hf[n * HSTR + t];
            pooled[l * DIM + t] = s;
        }
        // no sync needed here: next gather only READS Hf; zh_f writes are past mm2's sync
    }
    __syncthreads();

    // ---- classifier: relu(pooled @ wc1 + bc1) @ wc2 + bc2 ----
    float partial = 0.f;
    for (int j = t; j < 2 * 3 * DIM; j += 256) {
        float a = bc1[j];
        for (int i = 0; i < 3 * DIM; ++i) a = fmaf(pooled[i], wc1[i * 384 + j], a);
        partial += fmaxf(a, 0.f) * wc2[j];
    }
    partial += __shfl_xor(partial, 1);
    partial += __shfl_xor(partial, 2);
    partial += __shfl_xor(partial, 4);
    partial += __shfl_xor(partial, 8);
    partial += __shfl_xor(partial, 16);
    partial += __shfl_xor(partial, 32);
    if ((t & 63) == 0) red[t >> 6] = partial;
    __syncthreads();
    if (t == 0) out[b] = red[0] + red[1] + red[2] + red[3] + bc2[0];
}

extern "C" void kernel_launch(void* const* d_in, const int* in_sizes, int n_in,
                              void* d_out, int out_size, void* d_ws, size_t ws_size,
                              hipStream_t stream)
{
    const int*   x     = (const int*)d_in[0];
    const int*   los   = (const int*)d_in[1];
    const int*   eidx  = (const int*)d_in[2];
    const float* emb   = (const float*)d_in[3];
    const float* win1  = (const float*)d_in[4];
    const float* bin1  = (const float*)d_in[5];
    const float* gin_g = (const float*)d_in[6];
    const float* gin_b = (const float*)d_in[7];
    const float* win2  = (const float*)d_in[8];
    const float* bin2  = (const float*)d_in[9];
    const float* wh1   = (const float*)d_in[10];
    const float* bh1   = (const float*)d_in[11];
    const float* gh_g  = (const float*)d_in[12];
    const float* gh_b  = (const float*)d_in[13];
    const float* wh2   = (const float*)d_in[14];
    const float* bh2   = (const float*)d_in[15];
    const float* epsv  = (const float*)d_in[16];
    const float* wc1   = (const float*)d_in[17];
    const float* bc1   = (const float*)d_in[18];
    const float* wc2   = (const float*)d_in[19];
    const float* bc2   = (const float*)d_in[20];
    float* out = (float*)d_out;
    unsigned short* wsb = (unsigned short*)d_ws;

    hipLaunchKernelGGL(prep_w_kernel, dim3(4), dim3(256), 0, stream,
                       win1, win2, wh1, wh2, wsb);
    hipLaunchKernelGGL(gin_fused_kernel, dim3(NBATCH), dim3(256), 0, stream,
                       x, los, eidx, emb, bin1, gin_g, gin_b, bin2,
                       bh1, gh_g, gh_b, bh2, epsv, wc1, bc1, wc2, bc2,
                       (const unsigned short*)wsb, out);
}

// Round 3
// 96.331 us; speedup vs baseline: 4.3015x; 1.8451x over previous
//
#include <hip/hip_runtime.h>

#define NBATCH 4096
#define NNODE  32
#define NVOCAB 100
#define DIM    64
#define EPG    512
#define HSTR   68      // padded fp32 LDS row stride
#define LN_EPS 1e-5f

typedef float          f32x4  __attribute__((ext_vector_type(4)));
typedef unsigned int   u32x4  __attribute__((ext_vector_type(4)));
typedef __bf16         bf16x8 __attribute__((ext_vector_type(8)));

__device__ __forceinline__ float4 ldg4(const float* __restrict__ p) {
    return *reinterpret_cast<const float4*>(p);
}
__device__ __forceinline__ unsigned short f2bf(float f) {
    unsigned int u = __builtin_bit_cast(unsigned int, f);
    u += 0x7fffu + ((u >> 16) & 1u);            // round-to-nearest-even
    return (unsigned short)(u >> 16);
}
__device__ __forceinline__ float bf2f(unsigned short h) {
    unsigned int u = ((unsigned int)h) << 16;
    return __builtin_bit_cast(float, u);
}
__device__ __forceinline__ bf16x8 as_bf(u32x4 v) {
    return __builtin_bit_cast(bf16x8, v);
}

// ---- pre-kernel: split W into bf16 hi/lo and pack into MFMA B-fragment order ----
// fragment f = (s*4 + n)*64 + l  holds W[k = s*32 + (l>>4)*8 + j][col = n*16 + (l&15)], j=0..7
extern "C" __global__ void __launch_bounds__(256)
prep_w_kernel(const float* __restrict__ win1, const float* __restrict__ win2,
              const float* __restrict__ wh1,  const float* __restrict__ wh2,
              unsigned short* __restrict__ wsb)
{
    const float* Ws[4] = {win1, win2, wh1, wh2};
    const float* W = Ws[blockIdx.x];
    unsigned short* hi = wsb + blockIdx.x * 8192;
    unsigned short* lo = hi + 4096;
    for (int f = threadIdx.x; f < 512; f += 256) {
        const int s = f >> 8, n = (f >> 6) & 3, l = f & 63;
        const int g = l >> 4, c = l & 15, col = n * 16 + c;
        unsigned int uh[4], ul[4];
        #pragma unroll
        for (int j2 = 0; j2 < 4; ++j2) {
            unsigned short h2[2], l2[2];
            #pragma unroll
            for (int e = 0; e < 2; ++e) {
                const int j = j2 * 2 + e;
                const float v = W[(s * 32 + g * 8 + j) * DIM + col];
                h2[e] = f2bf(v);
                l2[e] = f2bf(v - bf2f(h2[e]));
            }
            uh[j2] = (unsigned int)h2[0] | ((unsigned int)h2[1] << 16);
            ul[j2] = (unsigned int)l2[0] | ((unsigned int)l2[1] << 16);
        }
        *(u32x4*)(hi + f * 8) = (u32x4){uh[0], uh[1], uh[2], uh[3]};
        *(u32x4*)(lo + f * 8) = (u32x4){ul[0], ul[1], ul[2], ul[3]};
    }
}

// ---- MFMA core: D(32x64) = Z(32x64) @ W(64x64), bf16x2-split, fp32 accum ----
__device__ __forceinline__ void mfma_mm(const unsigned int* __restrict__ zh,
                                        const unsigned int* __restrict__ zl,
                                        const unsigned short* __restrict__ wf,
                                        int m, int npair, int l,
                                        f32x4& acc0, f32x4& acc1)
{
    const u32x4 ah0 = *(const u32x4*)&zh[((0 * 2 + m) * 64 + l) * 4];
    const u32x4 ah1 = *(const u32x4*)&zh[((1 * 2 + m) * 64 + l) * 4];
    const u32x4 al0 = *(const u32x4*)&zl[((0 * 2 + m) * 64 + l) * 4];
    const u32x4 al1 = *(const u32x4*)&zl[((1 * 2 + m) * 64 + l) * 4];
    const unsigned short* wlo = wf + 4096;
    #pragma unroll
    for (int nn = 0; nn < 2; ++nn) {
        const int n = npair * 2 + nn;
        const u32x4 bh0 = *(const u32x4*)&wf [((0 * 4 + n) * 64 + l) * 8];
        const u32x4 bh1 = *(const u32x4*)&wf [((1 * 4 + n) * 64 + l) * 8];
        const u32x4 bl0 = *(const u32x4*)&wlo[((0 * 4 + n) * 64 + l) * 8];
        const u32x4 bl1 = *(const u32x4*)&wlo[((1 * 4 + n) * 64 + l) * 8];
        f32x4& acc = nn ? acc1 : acc0;
        acc = __builtin_amdgcn_mfma_f32_16x16x32_bf16(as_bf(ah0), as_bf(bh0), acc, 0, 0, 0);
        acc = __builtin_amdgcn_mfma_f32_16x16x32_bf16(as_bf(ah0), as_bf(bl0), acc, 0, 0, 0);
        acc = __builtin_amdgcn_mfma_f32_16x16x32_bf16(as_bf(al0), as_bf(bh0), acc, 0, 0, 0);
        acc = __builtin_amdgcn_mfma_f32_16x16x32_bf16(as_bf(ah1), as_bf(bh1), acc, 0, 0, 0);
        acc = __builtin_amdgcn_mfma_f32_16x16x32_bf16(as_bf(ah1), as_bf(bl1), acc, 0, 0, 0);
        acc = __builtin_amdgcn_mfma_f32_16x16x32_bf16(as_bf(al1), as_bf(bh1), acc, 0, 0, 0);
    }
}

extern "C" __global__ void __launch_bounds__(256)
gin_fused_kernel(const int* __restrict__ x, const int* __restrict__ los,
                 const int* __restrict__ eidx, const float* __restrict__ emb,
                 const float* __restrict__ bin1,
                 const float* __restrict__ gin_g, const float* __restrict__ gin_b,
                 const float* __restrict__ bin2,
                 const float* __restrict__ bh1,
                 const float* __restrict__ gh_g, const float* __restrict__ gh_b,
                 const float* __restrict__ bh2,
                 const float* __restrict__ epsv,
                 const float* __restrict__ wc1, const float* __restrict__ bc1,
                 const float* __restrict__ wc2, const float* __restrict__ bc2,
                 const unsigned short* __restrict__ wsb,
                 float* __restrict__ out)
{
    __shared__ __align__(16) float Hf[NNODE * HSTR];   // fp32 node features / z / layer out
    __shared__ __align__(16) unsigned int fh[1024];    // bf16-hi frags (H B-frags, then z/y A-frags); pre-loop: A_cnt histogram
    __shared__ __align__(16) unsigned int fl[1024];    // bf16-lo frags
    __shared__ __align__(16) unsigned int Af_h[512];   // adjacency A-frags hi (2 m-tiles)
    __shared__ __align__(16) unsigned int Af_l[512];   // adjacency A-frags lo
    __shared__ float pooled[3 * DIM];
    __shared__ float red[4];

    const int b = blockIdx.x;
    const int t = threadIdx.x;

    int* A_cnt = (int*)fh;          // 1024 ints, alias of fh (dead before first frag use)
    #pragma unroll
    for (int i = 0; i < 4; ++i) A_cnt[t + i * 256] = 0;
    __syncthreads();

    // ---- edges -> dense 32x32 count matrix (integer atomics: deterministic) ----
    const int ebase = b * EPG;
    const int goff  = b * NNODE;
    {
        const int s0 = eidx[ebase + t] - goff;
        const int d0 = eidx[NBATCH * EPG + ebase + t] - goff;
        const int s1 = eidx[ebase + 256 + t] - goff;
        const int d1 = eidx[NBATCH * EPG + ebase + 256 + t] - goff;
        atomicAdd(&A_cnt[d0 * NNODE + s0], 1);
        atomicAdd(&A_cnt[d1 * NNODE + s1], 1);
    }

    // ---- embedding lookup -> Hf ----
    for (int i = t; i < NNODE * 16; i += 256) {
        const int n = i >> 4, q = i & 15;
        const int idx = (n < (NNODE - 1)) ? x[b * (NNODE - 1) + n] : los[b];
        const float4 v = ldg4(emb + ((size_t)(n * NVOCAB + idx)) * DIM + q * 4);
        *reinterpret_cast<float4*>(&Hf[n * HSTR + q * 4]) = v;
    }
    __syncthreads();

    // ---- adjacency A-frags (built once; counts <=512 exact in hi+lo) ----
    {
        const int m = t >> 7, ll = (t >> 1) & 63, jh = t & 1;
        const int rowA = m * 16 + (ll & 15);
        const int kb = (ll >> 4) * 8 + jh * 4;
        unsigned int uh[2], ul[2];
        #pragma unroll
        for (int p = 0; p < 2; ++p) {
            unsigned short hh[2], lo2[2];
            #pragma unroll
            for (int e = 0; e < 2; ++e) {
                const float v = (float)A_cnt[rowA * NNODE + kb + p * 2 + e];
                hh[e] = f2bf(v);
                lo2[e] = f2bf(v - bf2f(hh[e]));
            }
            uh[p] = (unsigned int)hh[0] | ((unsigned int)hh[1] << 16);
            ul[p] = (unsigned int)lo2[0] | ((unsigned int)lo2[1] << 16);
        }
        const int base = (m * 64 + ll) * 4 + jh * 2;
        uint2 wh_, wl_;
        wh_.x = uh[0]; wh_.y = uh[1];
        wl_.x = ul[0]; wl_.y = ul[1];
        *reinterpret_cast<uint2*>(&Af_h[base]) = wh_;
        *reinterpret_cast<uint2*>(&Af_l[base]) = wl_;
    }
    __syncthreads();   // A_cnt (=fh) reads done before fh is reused for frags

    const int l64   = t & 63;
    const int wv    = t >> 6;
    const int mtile = wv & 1;
    const int npair = wv >> 1;
    const int row8  = t >> 3;
    const int cg    = t & 7;
    const int cbase = cg * 8;
    const int cc    = l64 & 15;
    const int rbase = mtile * 16 + (l64 >> 4) * 4;
    const int c0    = npair * 32 + cc;
    const int c1    = c0 + 16;

    for (int l = 0; l < 3; ++l) {
        const float* B1 = (l == 0) ? bin1  : bh1;
        const float* Gg = (l == 0) ? gin_g : gh_g;
        const float* Gb = (l == 0) ? gin_b : gh_b;
        const float* B2 = (l == 0) ? bin2  : bh2;
        const unsigned short* W1f = wsb + (l == 0 ? 0 : 2) * 8192;
        const unsigned short* W2f = wsb + (l == 0 ? 1 : 3) * 8192;
        const float sc = 1.0f + epsv[l];

        // ---- P1: H -> bf16 hi/lo B-frags (K=src node, N=dim) ----
        {
            const int n = t >> 6, ll = t & 63;
            const int col = n * 16 + (ll & 15);
            const int k0 = (ll >> 4) * 8;
            unsigned int uh[4], ul[4];
            #pragma unroll
            for (int p = 0; p < 4; ++p) {
                unsigned short hh[2], lo2[2];
                #pragma unroll
                for (int e = 0; e < 2; ++e) {
                    const float v = Hf[(k0 + p * 2 + e) * HSTR + col];
                    hh[e] = f2bf(v);
                    lo2[e] = f2bf(v - bf2f(hh[e]));
                }
                uh[p] = (unsigned int)hh[0] | ((unsigned int)hh[1] << 16);
                ul[p] = (unsigned int)lo2[0] | ((unsigned int)lo2[1] << 16);
            }
            *reinterpret_cast<u32x4*>(&fh[(n * 64 + ll) * 4]) = (u32x4){uh[0], uh[1], uh[2], uh[3]};
            *reinterpret_cast<u32x4*>(&fl[(n * 64 + ll) * 4]) = (u32x4){ul[0], ul[1], ul[2], ul[3]};
        }
        __syncthreads();

        // ---- P2: aggregation MFMA: z = sc*h + A_cnt @ H ----
        f32x4 zacc0, zacc1;
        {
            #pragma unroll
            for (int r = 0; r < 4; ++r) {
                zacc0[r] = sc * Hf[(rbase + r) * HSTR + c0];
                zacc1[r] = sc * Hf[(rbase + r) * HSTR + c1];
            }
            const u32x4 ah = *(const u32x4*)&Af_h[(mtile * 64 + l64) * 4];
            const u32x4 al = *(const u32x4*)&Af_l[(mtile * 64 + l64) * 4];
            #pragma unroll
            for (int nn = 0; nn < 2; ++nn) {
                const int n = npair * 2 + nn;
                const u32x4 bh = *(const u32x4*)&fh[(n * 64 + l64) * 4];
                const u32x4 bl = *(const u32x4*)&fl[(n * 64 + l64) * 4];
                f32x4& acc = nn ? zacc1 : zacc0;
                acc = __builtin_amdgcn_mfma_f32_16x16x32_bf16(as_bf(ah), as_bf(bh), acc, 0, 0, 0);
                acc = __builtin_amdgcn_mfma_f32_16x16x32_bf16(as_bf(ah), as_bf(bl), acc, 0, 0, 0);
                acc = __builtin_amdgcn_mfma_f32_16x16x32_bf16(as_bf(al), as_bf(bh), acc, 0, 0, 0);
            }
        }
        __syncthreads();   // seed reads of Hf complete before overwrite

        // ---- P2b: z -> Hf ----
        #pragma unroll
        for (int r = 0; r < 4; ++r) {
            Hf[(rbase + r) * HSTR + c0] = zacc0[r];
            Hf[(rbase + r) * HSTR + c1] = zacc1[r];
        }
        __syncthreads();

        // ---- P3: z -> bf16 hi/lo A-frags (M=node, K=dim) ----
        {
            const int s = t >> 7, m = (t >> 6) & 1, ll = t & 63;
            const int rowZ = m * 16 + (ll & 15);
            const int kb = s * 32 + (ll >> 4) * 8;
            const float4 v0 = *reinterpret_cast<const float4*>(&Hf[rowZ * HSTR + kb]);
            const float4 v1 = *reinterpret_cast<const float4*>(&Hf[rowZ * HSTR + kb + 4]);
            const float y[8] = { v0.x, v0.y, v0.z, v0.w, v1.x, v1.y, v1.z, v1.w };
            unsigned int uh[4], ul[4];
            #pragma unroll
            for (int j2 = 0; j2 < 4; ++j2) {
                unsigned short hh[2], lo2[2];
                #pragma unroll
                for (int e = 0; e < 2; ++e) {
                    const float v = y[j2 * 2 + e];
                    hh[e] = f2bf(v);
                    lo2[e] = f2bf(v - bf2f(hh[e]));
                }
                uh[j2] = (unsigned int)hh[0] | ((unsigned int)hh[1] << 16);
                ul[j2] = (unsigned int)lo2[0] | ((unsigned int)lo2[1] << 16);
            }
            *reinterpret_cast<u32x4*>(&fh[((s * 2 + m) * 64 + ll) * 4]) = (u32x4){uh[0], uh[1], uh[2], uh[3]};
            *reinterpret_cast<u32x4*>(&fl[((s * 2 + m) * 64 + ll) * 4]) = (u32x4){ul[0], ul[1], ul[2], ul[3]};
        }
        __syncthreads();

        // ---- P4: matmul1 via MFMA -> Hf (fp32, +bias) ----
        {
            f32x4 acc0 = {0.f, 0.f, 0.f, 0.f}, acc1 = {0.f, 0.f, 0.f, 0.f};
            mfma_mm(fh, fl, W1f, mtile, npair, l64, acc0, acc1);
            const float bb0 = B1[c0], bb1 = B1[c1];
            #pragma unroll
            for (int r = 0; r < 4; ++r) {
                Hf[(rbase + r) * HSTR + c0] = acc0[r] + bb0;
                Hf[(rbase + r) * HSTR + c1] = acc1[r] + bb1;
            }
        }
        __syncthreads();

        // ---- P5: LayerNorm + relu -> y bf16 hi/lo A-frags ----
        {
            const float4 v0 = *reinterpret_cast<const float4*>(&Hf[row8 * HSTR + cbase]);
            const float4 v1 = *reinterpret_cast<const float4*>(&Hf[row8 * HSTR + cbase + 4]);
            float y[8] = { v0.x, v0.y, v0.z, v0.w, v1.x, v1.y, v1.z, v1.w };
            float sum1 = 0.f, sum2 = 0.f;
            #pragma unroll
            for (int j = 0; j < 8; ++j) { sum1 += y[j]; sum2 += y[j] * y[j]; }
            sum1 += __shfl_xor(sum1, 1); sum1 += __shfl_xor(sum1, 2); sum1 += __shfl_xor(sum1, 4);
            sum2 += __shfl_xor(sum2, 1); sum2 += __shfl_xor(sum2, 2); sum2 += __shfl_xor(sum2, 4);
            const float mu  = sum1 * (1.0f / 64.0f);
            const float var = sum2 * (1.0f / 64.0f) - mu * mu;
            const float inv = rsqrtf(var + LN_EPS);
            const float4 gg0 = ldg4(Gg + cbase), gg1 = ldg4(Gg + cbase + 4);
            const float4 gb0 = ldg4(Gb + cbase), gb1 = ldg4(Gb + cbase + 4);
            const float ggs[8] = { gg0.x, gg0.y, gg0.z, gg0.w, gg1.x, gg1.y, gg1.z, gg1.w };
            const float gbs[8] = { gb0.x, gb0.y, gb0.z, gb0.w, gb1.x, gb1.y, gb1.z, gb1.w };
            unsigned int uh[4], ul[4];
            #pragma unroll
            for (int j2 = 0; j2 < 4; ++j2) {
                unsigned short hh[2], ll2[2];
                #pragma unroll
                for (int e = 0; e < 2; ++e) {
                    const int j = j2 * 2 + e;
                    const float v = fmaxf((y[j] - mu) * inv * ggs[j] + gbs[j], 0.f);
                    hh[e] = f2bf(v);
                    ll2[e] = f2bf(v - bf2f(hh[e]));
                }
                uh[j2] = (unsigned int)hh[0] | ((unsigned int)hh[1] << 16);
                ul[j2] = (unsigned int)ll2[0] | ((unsigned int)ll2[1] << 16);
            }
            const int s_ = cg >> 2, g_ = cg & 3, m_ = row8 >> 4, c_ = row8 & 15;
            const int fi = (s_ * 2 + m_) * 64 + g_ * 16 + c_;
            *reinterpret_cast<u32x4*>(&fh[fi * 4]) = (u32x4){uh[0], uh[1], uh[2], uh[3]};
            *reinterpret_cast<u32x4*>(&fl[fi * 4]) = (u32x4){ul[0], ul[1], ul[2], ul[3]};
        }
        __syncthreads();

        // ---- P6: matmul2 via MFMA -> Hf (fp32, +bias) = layer output ----
        {
            f32x4 acc0 = {0.f, 0.f, 0.f, 0.f}, acc1 = {0.f, 0.f, 0.f, 0.f};
            mfma_mm(fh, fl, W2f, mtile, npair, l64, acc0, acc1);
            const float bb0 = B2[c0], bb1 = B2[c1];
            #pragma unroll
            for (int r = 0; r < 4; ++r) {
                Hf[(rbase + r) * HSTR + c0] = acc0[r] + bb0;
                Hf[(rbase + r) * HSTR + c1] = acc1[r] + bb1;
            }
        }
        __syncthreads();

        // ---- P7: pooled[l][d] = sum over nodes (merged into next P1's phase) ----
        if (t < DIM) {
            float s = 0.f;
            #pragma unroll
            for (int n = 0; n < NNODE; ++n) s += Hf[n * HSTR + t];
            pooled[l * DIM + t] = s;
        }
    }
    __syncthreads();

    // ---- classifier: relu(pooled @ wc1 + bc1) @ wc2 + bc2 ----
    float partial = 0.f;
    for (int j = t; j < 2 * 3 * DIM; j += 256) {
        float a = bc1[j];
        for (int i = 0; i < 3 * DIM; ++i) a = fmaf(pooled[i], wc1[i * 384 + j], a);
        partial += fmaxf(a, 0.f) * wc2[j];
    }
    partial += __shfl_xor(partial, 1);
    partial += __shfl_xor(partial, 2);
    partial += __shfl_xor(partial, 4);
    partial += __shfl_xor(partial, 8);
    partial += __shfl_xor(partial, 16);
    partial += __shfl_xor(partial, 32);
    if ((t & 63) == 0) red[t >> 6] = partial;
    __syncthreads();
    if (t == 0) out[b] = red[0] + red[1] + red[2] + red[3] + bc2[0];
}

extern "C" void kernel_launch(void* const* d_in, const int* in_sizes, int n_in,
                              void* d_out, int out_size, void* d_ws, size_t ws_size,
                              hipStream_t stream)
{
    const int*   x     = (const int*)d_in[0];
    const int*   los   = (const int*)d_in[1];
    const int*   eidx  = (const int*)d_in[2];
    const float* emb   = (const float*)d_in[3];
    const float* win1  = (const float*)d_in[4];
    const float* bin1  = (const float*)d_in[5];
    const float* gin_g = (const float*)d_in[6];
    const float* gin_b = (const float*)d_in[7];
    const float* win2  = (const float*)d_in[8];
    const float* bin2  = (const float*)d_in[9];
    const float* wh1   = (const float*)d_in[10];
    const float* bh1   = (const float*)d_in[11];
    const float* gh_g  = (const float*)d_in[12];
    const float* gh_b  = (const float*)d_in[13];
    const float* wh2   = (const float*)d_in[14];
    const float* bh2   = (const float*)d_in[15];
    const float* epsv  = (const float*)d_in[16];
    const float* wc1   = (const float*)d_in[17];
    const float* bc1   = (const float*)d_in[18];
    const float* wc2   = (const float*)d_in[19];
    const float* bc2   = (const float*)d_in[20];
    float* out = (float*)d_out;
    unsigned short* wsb = (unsigned short*)d_ws;

    hipLaunchKernelGGL(prep_w_kernel, dim3(4), dim3(256), 0, stream,
                       win1, win2, wh1, wh2, wsb);
    hipLaunchKernelGGL(gin_fused_kernel, dim3(NBATCH), dim3(256), 0, stream,
                       x, los, eidx, emb, bin1, gin_g, gin_b, bin2,
                       bh1, gh_g, gh_b, bh2, epsv, wc1, bc1, wc2, bc2,
                       (const unsigned short*)wsb, out);
}

// Round 4
// 87.677 us; speedup vs baseline: 4.7262x; 1.0987x over previous
//
#include <hip/hip_runtime.h>

#define NBATCH 4096
#define NNODE  32
#define NVOCAB 100
#define DIM    64
#define EPG    512
#define HSTR   68      // padded fp32 LDS row stride
#define LN_EPS 1e-5f
#define CDIM   192     // 3*DIM
#define C2DIM  384     // classifier hidden

// workspace layout (bytes)
#define WS_WFRAG_OFF   0         // 4 x 16 KB  W-matrix frags
#define WS_WC1_OFF     65536     // wc1 frags: hi 147456 B + lo 147456 B
#define WS_POOL_OFF    360448    // pooled 4096*192 f32 = 3145728 B

typedef float          f32x4  __attribute__((ext_vector_type(4)));
typedef unsigned int   u32x4  __attribute__((ext_vector_type(4)));
typedef __bf16         bf16x8 __attribute__((ext_vector_type(8)));

__device__ __forceinline__ float4 ldg4(const float* __restrict__ p) {
    return *reinterpret_cast<const float4*>(p);
}
__device__ __forceinline__ unsigned short f2bf(float f) {           // native RNE cvt
    return __builtin_bit_cast(unsigned short, static_cast<__bf16>(f));
}
__device__ __forceinline__ float bf2f(unsigned short h) {
    return static_cast<float>(__builtin_bit_cast(__bf16, h));
}
__device__ __forceinline__ unsigned int pk2(float a, float b) {     // 2xbf16 pack
    return (unsigned int)f2bf(a) | ((unsigned int)f2bf(b) << 16);
}
__device__ __forceinline__ unsigned int pk2lo(float a, float b, unsigned int hi) {
    const float ra = a - bf2f((unsigned short)(hi & 0xffff));
    const float rb = b - bf2f((unsigned short)(hi >> 16));
    return pk2(ra, rb);
}
__device__ __forceinline__ bf16x8 as_bf(u32x4 v) {
    return __builtin_bit_cast(bf16x8, v);
}

// ---- pre-kernel: pack weights into bf16 hi/lo MFMA B-fragments ----
// blocks 0..3: win1,win2,wh1,wh2 (64x64). blocks 4..15: wc1 (192x384).
extern "C" __global__ void __launch_bounds__(256)
prep_w_kernel(const float* __restrict__ win1, const float* __restrict__ win2,
              const float* __restrict__ wh1,  const float* __restrict__ wh2,
              const float* __restrict__ wc1,
              unsigned short* __restrict__ wsb, unsigned short* __restrict__ wc1f)
{
    const int blk = blockIdx.x;
    if (blk < 4) {
        const float* Ws[4] = {win1, win2, wh1, wh2};
        const float* W = Ws[blk];
        unsigned short* hi = wsb + blk * 8192;
        unsigned short* lo = hi + 4096;
        for (int f = threadIdx.x; f < 512; f += 256) {
            const int s = f >> 8, n = (f >> 6) & 3, l = f & 63;
            const int g = l >> 4, c = l & 15, col = n * 16 + c;
            unsigned int uh[4], ul[4];
            #pragma unroll
            for (int j2 = 0; j2 < 4; ++j2) {
                const float a = W[(s * 32 + g * 8 + j2 * 2)     * DIM + col];
                const float b = W[(s * 32 + g * 8 + j2 * 2 + 1) * DIM + col];
                uh[j2] = pk2(a, b);
                ul[j2] = pk2lo(a, b, uh[j2]);
            }
            *(u32x4*)(hi + f * 8) = (u32x4){uh[0], uh[1], uh[2], uh[3]};
            *(u32x4*)(lo + f * 8) = (u32x4){ul[0], ul[1], ul[2], ul[3]};
        }
    } else {
        // wc1 frags: entry e = (s*24 + n)*64 + l holds wc1[k=s*32+(l>>4)*8+j][col=n*16+(l&15)]
        unsigned short* hi = wc1f;
        unsigned short* lo = wc1f + 6 * 24 * 64 * 8;   // 73728
        const int base = (blk - 4) * 768;
        for (int i = 0; i < 3; ++i) {
            const int e = base + i * 256 + threadIdx.x;
            const int s = e / (24 * 64), rem = e % (24 * 64);
            const int n = rem >> 6, l = rem & 63;
            const int col = n * 16 + (l & 15);
            const int k0 = s * 32 + (l >> 4) * 8;
            unsigned int uh[4], ul[4];
            #pragma unroll
            for (int j2 = 0; j2 < 4; ++j2) {
                const float a = wc1[(k0 + j2 * 2)     * C2DIM + col];
                const float b = wc1[(k0 + j2 * 2 + 1) * C2DIM + col];
                uh[j2] = pk2(a, b);
                ul[j2] = pk2lo(a, b, uh[j2]);
            }
            *(u32x4*)(hi + e * 8) = (u32x4){uh[0], uh[1], uh[2], uh[3]};
            *(u32x4*)(lo + e * 8) = (u32x4){ul[0], ul[1], ul[2], ul[3]};
        }
    }
}

// ---- MFMA core: D(32x64) = Z(32x64) @ W(64x64), bf16x2-split, fp32 accum ----
__device__ __forceinline__ void mfma_mm(const unsigned int* __restrict__ zh,
                                        const unsigned int* __restrict__ zl,
                                        const unsigned short* __restrict__ wf,
                                        int m, int npair, int l,
                                        f32x4& acc0, f32x4& acc1)
{
    const u32x4 ah0 = *(const u32x4*)&zh[((0 * 2 + m) * 64 + l) * 4];
    const u32x4 ah1 = *(const u32x4*)&zh[((1 * 2 + m) * 64 + l) * 4];
    const u32x4 al0 = *(const u32x4*)&zl[((0 * 2 + m) * 64 + l) * 4];
    const u32x4 al1 = *(const u32x4*)&zl[((1 * 2 + m) * 64 + l) * 4];
    const unsigned short* wlo = wf + 4096;
    #pragma unroll
    for (int nn = 0; nn < 2; ++nn) {
        const int n = npair * 2 + nn;
        const u32x4 bh0 = *(const u32x4*)&wf [((0 * 4 + n) * 64 + l) * 8];
        const u32x4 bh1 = *(const u32x4*)&wf [((1 * 4 + n) * 64 + l) * 8];
        const u32x4 bl0 = *(const u32x4*)&wlo[((0 * 4 + n) * 64 + l) * 8];
        const u32x4 bl1 = *(const u32x4*)&wlo[((1 * 4 + n) * 64 + l) * 8];
        f32x4& acc = nn ? acc1 : acc0;
        acc = __builtin_amdgcn_mfma_f32_16x16x32_bf16(as_bf(ah0), as_bf(bh0), acc, 0, 0, 0);
        acc = __builtin_amdgcn_mfma_f32_16x16x32_bf16(as_bf(ah0), as_bf(bl0), acc, 0, 0, 0);
        acc = __builtin_amdgcn_mfma_f32_16x16x32_bf16(as_bf(al0), as_bf(bh0), acc, 0, 0, 0);
        acc = __builtin_amdgcn_mfma_f32_16x16x32_bf16(as_bf(ah1), as_bf(bh1), acc, 0, 0, 0);
        acc = __builtin_amdgcn_mfma_f32_16x16x32_bf16(as_bf(ah1), as_bf(bl1), acc, 0, 0, 0);
        acc = __builtin_amdgcn_mfma_f32_16x16x32_bf16(as_bf(al1), as_bf(bh1), acc, 0, 0, 0);
    }
}

extern "C" __global__ void __launch_bounds__(256)
gin_fused_kernel(const int* __restrict__ x, const int* __restrict__ los,
                 const int* __restrict__ eidx, const float* __restrict__ emb,
                 const float* __restrict__ bin1,
                 const float* __restrict__ gin_g, const float* __restrict__ gin_b,
                 const float* __restrict__ bin2,
                 const float* __restrict__ bh1,
                 const float* __restrict__ gh_g, const float* __restrict__ gh_b,
                 const float* __restrict__ bh2,
                 const float* __restrict__ epsv,
                 const unsigned short* __restrict__ wsb,
                 float* __restrict__ pooled_ws)
{
    __shared__ __align__(16) float Hf[NNODE * HSTR];
    __shared__ __align__(16) unsigned int fh[1024];    // frags hi; pre-loop alias: A_cnt
    __shared__ __align__(16) unsigned int fl[1024];    // frags lo
    __shared__ __align__(16) unsigned int Af_h[512];   // adjacency A-frags (exact in bf16)
    __shared__ float pooled[3 * DIM];

    const int b = blockIdx.x;
    const int t = threadIdx.x;

    int* A_cnt = (int*)fh;
    #pragma unroll
    for (int i = 0; i < 4; ++i) A_cnt[t + i * 256] = 0;
    __syncthreads();

    // ---- edges -> dense 32x32 count matrix (int atomics: deterministic) ----
    const int ebase = b * EPG;
    const int goff  = b * NNODE;
    {
        const int s0 = eidx[ebase + t] - goff;
        const int d0 = eidx[NBATCH * EPG + ebase + t] - goff;
        const int s1 = eidx[ebase + 256 + t] - goff;
        const int d1 = eidx[NBATCH * EPG + ebase + 256 + t] - goff;
        atomicAdd(&A_cnt[d0 * NNODE + s0], 1);
        atomicAdd(&A_cnt[d1 * NNODE + s1], 1);
    }

    // ---- embedding lookup -> Hf ----
    for (int i = t; i < NNODE * 16; i += 256) {
        const int n = i >> 4, q = i & 15;
        const int idx = (n < (NNODE - 1)) ? x[b * (NNODE - 1) + n] : los[b];
        const float4 v = ldg4(emb + ((size_t)(n * NVOCAB + idx)) * DIM + q * 4);
        *reinterpret_cast<float4*>(&Hf[n * HSTR + q * 4]) = v;
    }
    __syncthreads();

    // ---- adjacency A-frags (counts are small ints: exact in bf16, no lo part) ----
    {
        const int m = t >> 7, ll = (t >> 1) & 63, jh = t & 1;
        const int rowA = m * 16 + (ll & 15);
        const int kb = (ll >> 4) * 8 + jh * 4;
        uint2 wh_;
        wh_.x = pk2((float)A_cnt[rowA * NNODE + kb],     (float)A_cnt[rowA * NNODE + kb + 1]);
        wh_.y = pk2((float)A_cnt[rowA * NNODE + kb + 2], (float)A_cnt[rowA * NNODE + kb + 3]);
        *reinterpret_cast<uint2*>(&Af_h[(m * 64 + ll) * 4 + jh * 2]) = wh_;
    }
    __syncthreads();   // A_cnt (=fh) reads done before fh reuse

    const int l64   = t & 63;
    const int wv    = t >> 6;
    const int mtile = wv & 1;
    const int npair = wv >> 1;
    const int row8  = t >> 3;
    const int cg    = t & 7;
    const int cbase = cg * 8;
    const int cc    = l64 & 15;
    const int rbase = mtile * 16 + (l64 >> 4) * 4;
    const int c0    = npair * 32 + cc;
    const int c1    = c0 + 16;

    for (int l = 0; l < 3; ++l) {
        const float* B1 = (l == 0) ? bin1  : bh1;
        const float* Gg = (l == 0) ? gin_g : gh_g;
        const float* Gb = (l == 0) ? gin_b : gh_b;
        const float* B2 = (l == 0) ? bin2  : bh2;
        const unsigned short* W1f = wsb + (l == 0 ? 0 : 2) * 8192;
        const unsigned short* W2f = wsb + (l == 0 ? 1 : 3) * 8192;
        const float sc = 1.0f + epsv[l];

        // ---- P1: H -> bf16 hi/lo B-frags (K=src node, N=dim) ----
        {
            const int n = t >> 6, ll = t & 63;
            const int col = n * 16 + (ll & 15);
            const int k0 = (ll >> 4) * 8;
            unsigned int uh[4], ul[4];
            #pragma unroll
            for (int p = 0; p < 4; ++p) {
                const float a = Hf[(k0 + p * 2)     * HSTR + col];
                const float bq = Hf[(k0 + p * 2 + 1) * HSTR + col];
                uh[p] = pk2(a, bq);
                ul[p] = pk2lo(a, bq, uh[p]);
            }
            *reinterpret_cast<u32x4*>(&fh[(n * 64 + ll) * 4]) = (u32x4){uh[0], uh[1], uh[2], uh[3]};
            *reinterpret_cast<u32x4*>(&fl[(n * 64 + ll) * 4]) = (u32x4){ul[0], ul[1], ul[2], ul[3]};
        }
        __syncthreads();

        // ---- P2: aggregation MFMA: z = sc*h + A_cnt @ H ----
        f32x4 zacc0, zacc1;
        {
            #pragma unroll
            for (int r = 0; r < 4; ++r) {
                zacc0[r] = sc * Hf[(rbase + r) * HSTR + c0];
                zacc1[r] = sc * Hf[(rbase + r) * HSTR + c1];
            }
            const u32x4 ah = *(const u32x4*)&Af_h[(mtile * 64 + l64) * 4];
            #pragma unroll
            for (int nn = 0; nn < 2; ++nn) {
                const int n = npair * 2 + nn;
                const u32x4 bh = *(const u32x4*)&fh[(n * 64 + l64) * 4];
                const u32x4 bl = *(const u32x4*)&fl[(n * 64 + l64) * 4];
                f32x4& acc = nn ? zacc1 : zacc0;
                acc = __builtin_amdgcn_mfma_f32_16x16x32_bf16(as_bf(ah), as_bf(bh), acc, 0, 0, 0);
                acc = __builtin_amdgcn_mfma_f32_16x16x32_bf16(as_bf(ah), as_bf(bl), acc, 0, 0, 0);
            }
        }
        __syncthreads();   // seed reads of Hf complete before overwrite

        // ---- P2b: z -> Hf ----
        #pragma unroll
        for (int r = 0; r < 4; ++r) {
            Hf[(rbase + r) * HSTR + c0] = zacc0[r];
            Hf[(rbase + r) * HSTR + c1] = zacc1[r];
        }
        __syncthreads();

        // ---- P3: z -> bf16 hi/lo A-frags (M=node, K=dim) ----
        {
            const int s = t >> 7, m = (t >> 6) & 1, ll = t & 63;
            const int rowZ = m * 16 + (ll & 15);
            const int kb = s * 32 + (ll >> 4) * 8;
            const float4 v0 = *reinterpret_cast<const float4*>(&Hf[rowZ * HSTR + kb]);
            const float4 v1 = *reinterpret_cast<const float4*>(&Hf[rowZ * HSTR + kb + 4]);
            const float y[8] = { v0.x, v0.y, v0.z, v0.w, v1.x, v1.y, v1.z, v1.w };
            unsigned int uh[4], ul[4];
            #pragma unroll
            for (int j2 = 0; j2 < 4; ++j2) {
                uh[j2] = pk2(y[j2 * 2], y[j2 * 2 + 1]);
                ul[j2] = pk2lo(y[j2 * 2], y[j2 * 2 + 1], uh[j2]);
            }
            *reinterpret_cast<u32x4*>(&fh[((s * 2 + m) * 64 + ll) * 4]) = (u32x4){uh[0], uh[1], uh[2], uh[3]};
            *reinterpret_cast<u32x4*>(&fl[((s * 2 + m) * 64 + ll) * 4]) = (u32x4){ul[0], ul[1], ul[2], ul[3]};
        }
        __syncthreads();

        // ---- P4: matmul1 via MFMA -> Hf (fp32, +bias) ----
        {
            f32x4 acc0 = {0.f, 0.f, 0.f, 0.f}, acc1 = {0.f, 0.f, 0.f, 0.f};
            mfma_mm(fh, fl, W1f, mtile, npair, l64, acc0, acc1);
            const float bb0 = B1[c0], bb1 = B1[c1];
            #pragma unroll
            for (int r = 0; r < 4; ++r) {
                Hf[(rbase + r) * HSTR + c0] = acc0[r] + bb0;
                Hf[(rbase + r) * HSTR + c1] = acc1[r] + bb1;
            }
        }
        __syncthreads();

        // ---- P5: LayerNorm + relu -> y bf16 hi/lo A-frags ----
        {
            const float4 v0 = *reinterpret_cast<const float4*>(&Hf[row8 * HSTR + cbase]);
            const float4 v1 = *reinterpret_cast<const float4*>(&Hf[row8 * HSTR + cbase + 4]);
            float y[8] = { v0.x, v0.y, v0.z, v0.w, v1.x, v1.y, v1.z, v1.w };
            float sum1 = 0.f, sum2 = 0.f;
            #pragma unroll
            for (int j = 0; j < 8; ++j) { sum1 += y[j]; sum2 += y[j] * y[j]; }
            sum1 += __shfl_xor(sum1, 1); sum1 += __shfl_xor(sum1, 2); sum1 += __shfl_xor(sum1, 4);
            sum2 += __shfl_xor(sum2, 1); sum2 += __shfl_xor(sum2, 2); sum2 += __shfl_xor(sum2, 4);
            const float mu  = sum1 * (1.0f / 64.0f);
            const float var = sum2 * (1.0f / 64.0f) - mu * mu;
            const float inv = rsqrtf(var + LN_EPS);
            const float4 gg0 = ldg4(Gg + cbase), gg1 = ldg4(Gg + cbase + 4);
            const float4 gb0 = ldg4(Gb + cbase), gb1 = ldg4(Gb + cbase + 4);
            const float ggs[8] = { gg0.x, gg0.y, gg0.z, gg0.w, gg1.x, gg1.y, gg1.z, gg1.w };
            const float gbs[8] = { gb0.x, gb0.y, gb0.z, gb0.w, gb1.x, gb1.y, gb1.z, gb1.w };
            #pragma unroll
            for (int j = 0; j < 8; ++j)
                y[j] = fmaxf((y[j] - mu) * inv * ggs[j] + gbs[j], 0.f);
            unsigned int uh[4], ul[4];
            #pragma unroll
            for (int j2 = 0; j2 < 4; ++j2) {
                uh[j2] = pk2(y[j2 * 2], y[j2 * 2 + 1]);
                ul[j2] = pk2lo(y[j2 * 2], y[j2 * 2 + 1], uh[j2]);
            }
            const int s_ = cg >> 2, g_ = cg & 3, m_ = row8 >> 4, c_ = row8 & 15;
            const int fi = (s_ * 2 + m_) * 64 + g_ * 16 + c_;
            *reinterpret_cast<u32x4*>(&fh[fi * 4]) = (u32x4){uh[0], uh[1], uh[2], uh[3]};
            *reinterpret_cast<u32x4*>(&fl[fi * 4]) = (u32x4){ul[0], ul[1], ul[2], ul[3]};
        }
        __syncthreads();

        // ---- P6: matmul2 via MFMA -> Hf (fp32, +bias) = layer output ----
        {
            f32x4 acc0 = {0.f, 0.f, 0.f, 0.f}, acc1 = {0.f, 0.f, 0.f, 0.f};
            mfma_mm(fh, fl, W2f, mtile, npair, l64, acc0, acc1);
            const float bb0 = B2[c0], bb1 = B2[c1];
            #pragma unroll
            for (int r = 0; r < 4; ++r) {
                Hf[(rbase + r) * HSTR + c0] = acc0[r] + bb0;
                Hf[(rbase + r) * HSTR + c1] = acc1[r] + bb1;
            }
        }
        __syncthreads();

        // ---- P7: pooled[l][d] = sum over nodes ----
        if (t < DIM) {
            float s = 0.f;
            #pragma unroll
            for (int n = 0; n < NNODE; ++n) s += Hf[n * HSTR + t];
            pooled[l * DIM + t] = s;
        }
    }
    __syncthreads();

    if (t < CDIM) pooled_ws[b * CDIM + t] = pooled[t];
}

// ---- classifier kernel: out = relu(pooled @ wc1 + bc1) @ wc2 + bc2 ----
// 256 blocks x 16 graphs; MFMA bf16-split; wc1 pre-packed frags from ws.
extern "C" __global__ void __launch_bounds__(256)
classifier_kernel(const float* __restrict__ pooled_ws,
                  const unsigned short* __restrict__ wc1f,
                  const float* __restrict__ bc1, const float* __restrict__ wc2,
                  const float* __restrict__ bc2, float* __restrict__ out)
{
    #define PSTR 196
    __shared__ __align__(16) float P[16 * PSTR];
    __shared__ __align__(16) unsigned int afh[6 * 64 * 4];  // A-frags hi (s=0..5)
    __shared__ __align__(16) unsigned int afl[6 * 64 * 4];
    __shared__ float rsum[4][16];

    const int b = blockIdx.x;
    const int t = threadIdx.x;
    const int l = t & 63;
    const int w = t >> 6;
    const unsigned short* wc1lo = wc1f + 73728;

    // stage pooled rows (coalesced)
    for (int i = t; i < 16 * 48; i += 256) {
        const int row = i / 48, q = i % 48;
        const float4 v = ldg4(pooled_ws + ((size_t)(b * 16 + row)) * CDIM + q * 4);
        *reinterpret_cast<float4*>(&P[row * PSTR + q * 4]) = v;
    }
    __syncthreads();

    // build A-frags: entry e = s*64 + l holds P[row=l&15][k=s*32+(l>>4)*8+j]
    for (int e = t; e < 6 * 64; e += 256) {
        const int s = e >> 6, ll = e & 63;
        const int row = ll & 15;
        const int k0 = s * 32 + (ll >> 4) * 8;
        const float4 v0 = *reinterpret_cast<const float4*>(&P[row * PSTR + k0]);
        const float4 v1 = *reinterpret_cast<const float4*>(&P[row * PSTR + k0 + 4]);
        const float y[8] = { v0.x, v0.y, v0.z, v0.w, v1.x, v1.y, v1.z, v1.w };
        unsigned int uh[4], ul[4];
        #pragma unroll
        for (int j2 = 0; j2 < 4; ++j2) {
            uh[j2] = pk2(y[j2 * 2], y[j2 * 2 + 1]);
            ul[j2] = pk2lo(y[j2 * 2], y[j2 * 2 + 1], uh[j2]);
        }
        *reinterpret_cast<u32x4*>(&afh[e * 4]) = (u32x4){uh[0], uh[1], uh[2], uh[3]};
        *reinterpret_cast<u32x4*>(&afl[e * 4]) = (u32x4){ul[0], ul[1], ul[2], ul[3]};
    }
    __syncthreads();

    // wave w: n-tiles 6w .. 6w+5 (16 cols each)
    float part[4] = {0.f, 0.f, 0.f, 0.f};
    for (int nt = 0; nt < 6; ++nt) {
        const int n = w * 6 + nt;
        f32x4 acc = {0.f, 0.f, 0.f, 0.f};
        #pragma unroll
        for (int s = 0; s < 6; ++s) {
            const u32x4 ah = *(const u32x4*)&afh[(s * 64 + l) * 4];
            const u32x4 al = *(const u32x4*)&afl[(s * 64 + l) * 4];
            const u32x4 bh = *(const u32x4*)&wc1f [((s * 24 + n) * 64 + l) * 8];
            const u32x4 bl = *(const u32x4*)&wc1lo[((s * 24 + n) * 64 + l) * 8];
            acc = __builtin_amdgcn_mfma_f32_16x16x32_bf16(as_bf(ah), as_bf(bh), acc, 0, 0, 0);
            acc = __builtin_amdgcn_mfma_f32_16x16x32_bf16(as_bf(ah), as_bf(bl), acc, 0, 0, 0);
            acc = __builtin_amdgcn_mfma_f32_16x16x32_bf16(as_bf(al), as_bf(bh), acc, 0, 0, 0);
        }
        const int col = n * 16 + (l & 15);
        const float bias = bc1[col], w2 = wc2[col];
        #pragma unroll
        for (int r = 0; r < 4; ++r)
            part[r] += fmaxf(acc[r] + bias, 0.f) * w2;
    }
    // reduce over the 16 lanes (same rows, different cols)
    #pragma unroll
    for (int r = 0; r < 4; ++r) {
        part[r] += __shfl_xor(part[r], 1);
        part[r] += __shfl_xor(part[r], 2);
        part[r] += __shfl_xor(part[r], 4);
        part[r] += __shfl_xor(part[r], 8);
    }
    if ((l & 15) == 0) {
        const int g = l >> 4;
        #pragma unroll
        for (int r = 0; r < 4; ++r) rsum[w][g * 4 + r] = part[r];
    }
    __syncthreads();
    if (t < 16)
        out[b * 16 + t] = rsum[0][t] + rsum[1][t] + rsum[2][t] + rsum[3][t] + bc2[0];
}

extern "C" void kernel_launch(void* const* d_in, const int* in_sizes, int n_in,
                              void* d_out, int out_size, void* d_ws, size_t ws_size,
                              hipStream_t stream)
{
    const int*   x     = (const int*)d_in[0];
    const int*   los   = (const int*)d_in[1];
    const int*   eidx  = (const int*)d_in[2];
    const float* emb   = (const float*)d_in[3];
    const float* win1  = (const float*)d_in[4];
    const float* bin1  = (const float*)d_in[5];
    const float* gin_g = (const float*)d_in[6];
    const float* gin_b = (const float*)d_in[7];
    const float* win2  = (const float*)d_in[8];
    const float* bin2  = (const float*)d_in[9];
    const float* wh1   = (const float*)d_in[10];
    const float* bh1   = (const float*)d_in[11];
    const float* gh_g  = (const float*)d_in[12];
    const float* gh_b  = (const float*)d_in[13];
    const float* wh2   = (const float*)d_in[14];
    const float* bh2   = (const float*)d_in[15];
    const float* epsv  = (const float*)d_in[16];
    const float* wc1   = (const float*)d_in[17];
    const float* bc1   = (const float*)d_in[18];
    const float* wc2   = (const float*)d_in[19];
    const float* bc2   = (const float*)d_in[20];
    float* out = (float*)d_out;

    unsigned short* wsb      = (unsigned short*)((char*)d_ws + WS_WFRAG_OFF);
    unsigned short* wc1f     = (unsigned short*)((char*)d_ws + WS_WC1_OFF);
    float*          pooledws = (float*)((char*)d_ws + WS_POOL_OFF);

    hipLaunchKernelGGL(prep_w_kernel, dim3(16), dim3(256), 0, stream,
                       win1, win2, wh1, wh2, wc1, wsb, wc1f);
    hipLaunchKernelGGL(gin_fused_kernel, dim3(NBATCH), dim3(256), 0, stream,
                       x, los, eidx, emb, bin1, gin_g, gin_b, bin2,
                       bh1, gh_g, gh_b, bh2, epsv,
                       (const unsigned short*)wsb, pooledws);
    hipLaunchKernelGGL(classifier_kernel, dim3(NBATCH / 16), dim3(256), 0, stream,
                       (const float*)pooledws, (const unsigned short*)wc1f,
                       bc1, wc2, bc2, out);
}

// Round 6
// 73.861 us; speedup vs baseline: 5.6102x; 1.1870x over previous
//
#include <hip/hip_runtime.h>

#define NBATCH 4096
#define NNODE  32
#define NVOCAB 100
#define DIM    64
#define EPG    512
#define HSTR   68      // padded fp32 LDS row stride
#define LN_EPS 1e-5f
#define CDIM   192     // 3*DIM
#define C2DIM  384     // classifier hidden
#define GPB    2       // graphs per block (main kernel)

// workspace layout (bytes)
#define WS_WFRAG_OFF   0         // 4 x 16 KB  W-matrix frags
#define WS_WC1_OFF     65536     // wc1 frags: hi 147456 B + lo 147456 B
#define WS_POOL_OFF    360448    // pooled 4096*192 f32 = 3145728 B

typedef float          f32x4  __attribute__((ext_vector_type(4)));
typedef unsigned int   u32x4  __attribute__((ext_vector_type(4)));
typedef __bf16         bf16x8 __attribute__((ext_vector_type(8)));

__device__ __forceinline__ float4 ldg4(const float* __restrict__ p) {
    return *reinterpret_cast<const float4*>(p);
}
__device__ __forceinline__ unsigned short f2bf(float f) {           // native RNE cvt
    return __builtin_bit_cast(unsigned short, static_cast<__bf16>(f));
}
__device__ __forceinline__ float bf2f(unsigned short h) {
    return static_cast<float>(__builtin_bit_cast(__bf16, h));
}
__device__ __forceinline__ unsigned int pk2(float a, float b) {     // 2xbf16 pack
    return (unsigned int)f2bf(a) | ((unsigned int)f2bf(b) << 16);
}
__device__ __forceinline__ unsigned int pk2lo(float a, float b, unsigned int hi) {
    const float ra = a - bf2f((unsigned short)(hi & 0xffff));
    const float rb = b - bf2f((unsigned short)(hi >> 16));
    return pk2(ra, rb);
}
__device__ __forceinline__ bf16x8 as_bf(u32x4 v) {
    return __builtin_bit_cast(bf16x8, v);
}

// ---- pre-kernel: pack weights into bf16 hi/lo MFMA B-fragments ----
// blocks 0..3: win1,win2,wh1,wh2 (64x64). blocks 4..15: wc1 (192x384).
extern "C" __global__ void __launch_bounds__(256)
prep_w_kernel(const float* __restrict__ win1, const float* __restrict__ win2,
              const float* __restrict__ wh1,  const float* __restrict__ wh2,
              const float* __restrict__ wc1,
              unsigned short* __restrict__ wsb, unsigned short* __restrict__ wc1f)
{
    const int blk = blockIdx.x;
    if (blk < 4) {
        const float* Ws[4] = {win1, win2, wh1, wh2};
        const float* W = Ws[blk];
        unsigned short* hi = wsb + blk * 8192;
        unsigned short* lo = hi + 4096;
        for (int f = threadIdx.x; f < 512; f += 256) {
            const int s = f >> 8, n = (f >> 6) & 3, l = f & 63;
            const int g = l >> 4, c = l & 15, col = n * 16 + c;
            unsigned int uh[4], ul[4];
            #pragma unroll
            for (int j2 = 0; j2 < 4; ++j2) {
                const float a = W[(s * 32 + g * 8 + j2 * 2)     * DIM + col];
                const float b = W[(s * 32 + g * 8 + j2 * 2 + 1) * DIM + col];
                uh[j2] = pk2(a, b);
                ul[j2] = pk2lo(a, b, uh[j2]);
            }
            *(u32x4*)(hi + f * 8) = (u32x4){uh[0], uh[1], uh[2], uh[3]};
            *(u32x4*)(lo + f * 8) = (u32x4){ul[0], ul[1], ul[2], ul[3]};
        }
    } else {
        // wc1 frags: entry e = (s*24 + n)*64 + l holds wc1[k=s*32+(l>>4)*8+j][col=n*16+(l&15)]
        unsigned short* hi = wc1f;
        unsigned short* lo = wc1f + 6 * 24 * 64 * 8;   // 73728
        const int base = (blk - 4) * 768;
        for (int i = 0; i < 3; ++i) {
            const int e = base + i * 256 + threadIdx.x;
            const int s = e / (24 * 64), rem = e % (24 * 64);
            const int n = rem >> 6, l = rem & 63;
            const int col = n * 16 + (l & 15);
            const int k0 = s * 32 + (l >> 4) * 8;
            unsigned int uh[4], ul[4];
            #pragma unroll
            for (int j2 = 0; j2 < 4; ++j2) {
                const float a = wc1[(k0 + j2 * 2)     * C2DIM + col];
                const float b = wc1[(k0 + j2 * 2 + 1) * C2DIM + col];
                uh[j2] = pk2(a, b);
                ul[j2] = pk2lo(a, b, uh[j2]);
            }
            *(u32x4*)(hi + e * 8) = (u32x4){uh[0], uh[1], uh[2], uh[3]};
            *(u32x4*)(lo + e * 8) = (u32x4){ul[0], ul[1], ul[2], ul[3]};
        }
    }
}

// ---- MFMA core: D(32x64) = Z(32x64) @ W(64x64), bf16x2-split, fp32 accum ----
__device__ __forceinline__ void mfma_mm(const unsigned int* __restrict__ zh,
                                        const unsigned int* __restrict__ zl,
                                        const unsigned short* __restrict__ wf,
                                        int m, int npair, int l,
                                        f32x4& acc0, f32x4& acc1)
{
    const u32x4 ah0 = *(const u32x4*)&zh[((0 * 2 + m) * 64 + l) * 4];
    const u32x4 ah1 = *(const u32x4*)&zh[((1 * 2 + m) * 64 + l) * 4];
    const u32x4 al0 = *(const u32x4*)&zl[((0 * 2 + m) * 64 + l) * 4];
    const u32x4 al1 = *(const u32x4*)&zl[((1 * 2 + m) * 64 + l) * 4];
    const unsigned short* wlo = wf + 4096;
    #pragma unroll
    for (int nn = 0; nn < 2; ++nn) {
        const int n = npair * 2 + nn;
        const u32x4 bh0 = *(const u32x4*)&wf [((0 * 4 + n) * 64 + l) * 8];
        const u32x4 bh1 = *(const u32x4*)&wf [((1 * 4 + n) * 64 + l) * 8];
        const u32x4 bl0 = *(const u32x4*)&wlo[((0 * 4 + n) * 64 + l) * 8];
        const u32x4 bl1 = *(const u32x4*)&wlo[((1 * 4 + n) * 64 + l) * 8];
        f32x4& acc = nn ? acc1 : acc0;
        acc = __builtin_amdgcn_mfma_f32_16x16x32_bf16(as_bf(ah0), as_bf(bh0), acc, 0, 0, 0);
        acc = __builtin_amdgcn_mfma_f32_16x16x32_bf16(as_bf(ah0), as_bf(bl0), acc, 0, 0, 0);
        acc = __builtin_amdgcn_mfma_f32_16x16x32_bf16(as_bf(al0), as_bf(bh0), acc, 0, 0, 0);
        acc = __builtin_amdgcn_mfma_f32_16x16x32_bf16(as_bf(ah1), as_bf(bh1), acc, 0, 0, 0);
        acc = __builtin_amdgcn_mfma_f32_16x16x32_bf16(as_bf(ah1), as_bf(bl1), acc, 0, 0, 0);
        acc = __builtin_amdgcn_mfma_f32_16x16x32_bf16(as_bf(al1), as_bf(bh1), acc, 0, 0, 0);
    }
}

extern "C" __global__ void __launch_bounds__(256, 4)
gin_fused_kernel(const int* __restrict__ x, const int* __restrict__ los,
                 const int* __restrict__ eidx, const float* __restrict__ emb,
                 const float* __restrict__ bin1,
                 const float* __restrict__ gin_g, const float* __restrict__ gin_b,
                 const float* __restrict__ bin2,
                 const float* __restrict__ bh1,
                 const float* __restrict__ gh_g, const float* __restrict__ gh_b,
                 const float* __restrict__ bh2,
                 const float* __restrict__ epsv,
                 const unsigned short* __restrict__ wsb,
                 float* __restrict__ pooled_ws)
{
    __shared__ __align__(16) float Hf[GPB * NNODE * HSTR];   // 64 rows fp32
    __shared__ __align__(16) unsigned int fh[GPB][1024];     // frags hi; pre-loop alias: A_cnt (both graphs)
    __shared__ __align__(16) unsigned int fl[GPB][1024];     // frags lo
    __shared__ __align__(16) unsigned int Af_h[GPB][512];    // adjacency A-frags
    __shared__ float pooled[GPB][3 * DIM];

    const int b2 = blockIdx.x;
    const int t = threadIdx.x;

    int* A_cnt = (int*)&fh[0][0];          // GPB*1024 ints (spans fh[0..GPB-1])
    #pragma unroll
    for (int i = 0; i < 4 * GPB; ++i) A_cnt[t + i * 256] = 0;
    __syncthreads();

    // ---- edges -> dense 32x32 count matrices (int atomics: deterministic) ----
    #pragma unroll
    for (int g = 0; g < GPB; ++g) {
        const int b = b2 * GPB + g;
        const int ebase = b * EPG;
        const int goff  = b * NNODE;
        const int s0 = eidx[ebase + t] - goff;
        const int d0 = eidx[NBATCH * EPG + ebase + t] - goff;
        const int s1 = eidx[ebase + 256 + t] - goff;
        const int d1 = eidx[NBATCH * EPG + ebase + 256 + t] - goff;
        atomicAdd(&A_cnt[g * 1024 + d0 * NNODE + s0], 1);
        atomicAdd(&A_cnt[g * 1024 + d1 * NNODE + s1], 1);
    }

    // ---- embedding lookup -> Hf (64 rows) ----
    for (int i = t; i < GPB * NNODE * 16; i += 256) {
        const int n64 = i >> 4, q = i & 15;
        const int g = n64 >> 5, n = n64 & 31;
        const int b = b2 * GPB + g;
        const int idx = (n < (NNODE - 1)) ? x[b * (NNODE - 1) + n] : los[b];
        const float4 v = ldg4(emb + ((size_t)(n * NVOCAB + idx)) * DIM + q * 4);
        *reinterpret_cast<float4*>(&Hf[n64 * HSTR + q * 4]) = v;
    }
    __syncthreads();

    // ---- adjacency A-frags (counts are small ints: exact in bf16) ----
    {
        const int m = t >> 7, ll = (t >> 1) & 63, jh = t & 1;
        const int rowA = m * 16 + (ll & 15);
        const int kb = (ll >> 4) * 8 + jh * 4;
        #pragma unroll
        for (int g = 0; g < GPB; ++g) {
            const int* ac = A_cnt + g * 1024 + rowA * NNODE + kb;
            uint2 wh_;
            wh_.x = pk2((float)ac[0], (float)ac[1]);
            wh_.y = pk2((float)ac[2], (float)ac[3]);
            *reinterpret_cast<uint2*>(&Af_h[g][(m * 64 + ll) * 4 + jh * 2]) = wh_;
        }
    }
    __syncthreads();   // A_cnt (=fh) reads done before fh reuse

    const int l64   = t & 63;
    const int wv    = t >> 6;
    const int mtile = wv & 1;
    const int npair = wv >> 1;
    const int row8  = t >> 3;              // 0..31
    const int cg    = t & 7;
    const int cbase = cg * 8;
    const int cc    = l64 & 15;
    const int rbase = mtile * 16 + (l64 >> 4) * 4;
    const int c0    = npair * 32 + cc;
    const int c1    = c0 + 16;

    for (int l = 0; l < 3; ++l) {
        const float* B1 = (l == 0) ? bin1  : bh1;
        const float* Gg = (l == 0) ? gin_g : gh_g;
        const float* Gb = (l == 0) ? gin_b : gh_b;
        const float* B2 = (l == 0) ? bin2  : bh2;
        const unsigned short* W1f = wsb + (l == 0 ? 0 : 2) * 8192;
        const unsigned short* W2f = wsb + (l == 0 ? 1 : 3) * 8192;
        const float sc = 1.0f + epsv[l];

        // ---- P1: H -> bf16 hi/lo B-frags (K=src node, N=dim) ----
        {
            const int n = t >> 6, ll = t & 63;
            const int col = n * 16 + (ll & 15);
            const int k0 = (ll >> 4) * 8;
            #pragma unroll
            for (int g = 0; g < GPB; ++g) {
                const float* H = Hf + g * NNODE * HSTR;
                unsigned int uh[4], ul[4];
                #pragma unroll
                for (int p = 0; p < 4; ++p) {
                    const float a  = H[(k0 + p * 2)     * HSTR + col];
                    const float bq = H[(k0 + p * 2 + 1) * HSTR + col];
                    uh[p] = pk2(a, bq);
                    ul[p] = pk2lo(a, bq, uh[p]);
                }
                *reinterpret_cast<u32x4*>(&fh[g][(n * 64 + ll) * 4]) = (u32x4){uh[0], uh[1], uh[2], uh[3]};
                *reinterpret_cast<u32x4*>(&fl[g][(n * 64 + ll) * 4]) = (u32x4){ul[0], ul[1], ul[2], ul[3]};
            }
        }
        __syncthreads();

        // ---- P2: aggregation MFMA: z = sc*h + A_cnt @ H ----
        f32x4 zacc0[GPB], zacc1[GPB];
        #pragma unroll
        for (int g = 0; g < GPB; ++g) {
            const float* H = Hf + g * NNODE * HSTR;
            #pragma unroll
            for (int r = 0; r < 4; ++r) {
                zacc0[g][r] = sc * H[(rbase + r) * HSTR + c0];
                zacc1[g][r] = sc * H[(rbase + r) * HSTR + c1];
            }
            const u32x4 ah = *(const u32x4*)&Af_h[g][(mtile * 64 + l64) * 4];
            #pragma unroll
            for (int nn = 0; nn < 2; ++nn) {
                const int n = npair * 2 + nn;
                const u32x4 bh = *(const u32x4*)&fh[g][(n * 64 + l64) * 4];
                const u32x4 bl = *(const u32x4*)&fl[g][(n * 64 + l64) * 4];
                f32x4& acc = nn ? zacc1[g] : zacc0[g];
                acc = __builtin_amdgcn_mfma_f32_16x16x32_bf16(as_bf(ah), as_bf(bh), acc, 0, 0, 0);
                acc = __builtin_amdgcn_mfma_f32_16x16x32_bf16(as_bf(ah), as_bf(bl), acc, 0, 0, 0);
            }
        }
        __syncthreads();   // seed reads of Hf complete before overwrite

        // ---- P2b: z -> Hf ----
        #pragma unroll
        for (int g = 0; g < GPB; ++g) {
            float* H = Hf + g * NNODE * HSTR;
            #pragma unroll
            for (int r = 0; r < 4; ++r) {
                H[(rbase + r) * HSTR + c0] = zacc0[g][r];
                H[(rbase + r) * HSTR + c1] = zacc1[g][r];
            }
        }
        __syncthreads();

        // ---- P3: z -> bf16 hi/lo A-frags (M=node, K=dim) ----
        {
            const int s = t >> 7, m = (t >> 6) & 1, ll = t & 63;
            const int rowZ = m * 16 + (ll & 15);
            const int kb = s * 32 + (ll >> 4) * 8;
            #pragma unroll
            for (int g = 0; g < GPB; ++g) {
                const float* H = Hf + g * NNODE * HSTR;
                const float4 v0 = *reinterpret_cast<const float4*>(&H[rowZ * HSTR + kb]);
                const float4 v1 = *reinterpret_cast<const float4*>(&H[rowZ * HSTR + kb + 4]);
                const float y[8] = { v0.x, v0.y, v0.z, v0.w, v1.x, v1.y, v1.z, v1.w };
                unsigned int uh[4], ul[4];
                #pragma unroll
                for (int j2 = 0; j2 < 4; ++j2) {
                    uh[j2] = pk2(y[j2 * 2], y[j2 * 2 + 1]);
                    ul[j2] = pk2lo(y[j2 * 2], y[j2 * 2 + 1], uh[j2]);
                }
                *reinterpret_cast<u32x4*>(&fh[g][((s * 2 + m) * 64 + ll) * 4]) = (u32x4){uh[0], uh[1], uh[2], uh[3]};
                *reinterpret_cast<u32x4*>(&fl[g][((s * 2 + m) * 64 + ll) * 4]) = (u32x4){ul[0], ul[1], ul[2], ul[3]};
            }
        }
        __syncthreads();

        // ---- P4: matmul1 via MFMA -> Hf (fp32, +bias) ----
        {
            const float bb0 = B1[c0], bb1 = B1[c1];
            #pragma unroll
            for (int g = 0; g < GPB; ++g) {
                f32x4 acc0 = {0.f, 0.f, 0.f, 0.f}, acc1 = {0.f, 0.f, 0.f, 0.f};
                mfma_mm(fh[g], fl[g], W1f, mtile, npair, l64, acc0, acc1);
                float* H = Hf + g * NNODE * HSTR;
                #pragma unroll
                for (int r = 0; r < 4; ++r) {
                    H[(rbase + r) * HSTR + c0] = acc0[r] + bb0;
                    H[(rbase + r) * HSTR + c1] = acc1[r] + bb1;
                }
            }
        }
        __syncthreads();

        // ---- P5: LayerNorm + relu -> y bf16 hi/lo A-frags ----
        {
            const float4 gg0 = ldg4(Gg + cbase), gg1 = ldg4(Gg + cbase + 4);
            const float4 gb0 = ldg4(Gb + cbase), gb1 = ldg4(Gb + cbase + 4);
            const float ggs[8] = { gg0.x, gg0.y, gg0.z, gg0.w, gg1.x, gg1.y, gg1.z, gg1.w };
            const float gbs[8] = { gb0.x, gb0.y, gb0.z, gb0.w, gb1.x, gb1.y, gb1.z, gb1.w };
            const int s_ = cg >> 2, g_ = cg & 3, m_ = row8 >> 4, c_ = row8 & 15;
            const int fi = (s_ * 2 + m_) * 64 + g_ * 16 + c_;
            #pragma unroll
            for (int g = 0; g < GPB; ++g) {
                const float* H = Hf + g * NNODE * HSTR;
                const float4 v0 = *reinterpret_cast<const float4*>(&H[row8 * HSTR + cbase]);
                const float4 v1 = *reinterpret_cast<const float4*>(&H[row8 * HSTR + cbase + 4]);
                float y[8] = { v0.x, v0.y, v0.z, v0.w, v1.x, v1.y, v1.z, v1.w };
                float sum1 = 0.f, sum2 = 0.f;
                #pragma unroll
                for (int j = 0; j < 8; ++j) { sum1 += y[j]; sum2 += y[j] * y[j]; }
                sum1 += __shfl_xor(sum1, 1); sum1 += __shfl_xor(sum1, 2); sum1 += __shfl_xor(sum1, 4);
                sum2 += __shfl_xor(sum2, 1); sum2 += __shfl_xor(sum2, 2); sum2 += __shfl_xor(sum2, 4);
                const float mu  = sum1 * (1.0f / 64.0f);
                const float var = sum2 * (1.0f / 64.0f) - mu * mu;
                const float inv = rsqrtf(var + LN_EPS);
                #pragma unroll
                for (int j = 0; j < 8; ++j)
                    y[j] = fmaxf((y[j] - mu) * inv * ggs[j] + gbs[j], 0.f);
                unsigned int uh[4], ul[4];
                #pragma unroll
                for (int j2 = 0; j2 < 4; ++j2) {
                    uh[j2] = pk2(y[j2 * 2], y[j2 * 2 + 1]);
                    ul[j2] = pk2lo(y[j2 * 2], y[j2 * 2 + 1], uh[j2]);
                }
                *reinterpret_cast<u32x4*>(&fh[g][fi * 4]) = (u32x4){uh[0], uh[1], uh[2], uh[3]};
                *reinterpret_cast<u32x4*>(&fl[g][fi * 4]) = (u32x4){ul[0], ul[1], ul[2], ul[3]};
            }
        }
        __syncthreads();

        // ---- P6: matmul2 via MFMA -> Hf (fp32, +bias) = layer output ----
        {
            const float bb0 = B2[c0], bb1 = B2[c1];
            #pragma unroll
            for (int g = 0; g < GPB; ++g) {
                f32x4 acc0 = {0.f, 0.f, 0.f, 0.f}, acc1 = {0.f, 0.f, 0.f, 0.f};
                mfma_mm(fh[g], fl[g], W2f, mtile, npair, l64, acc0, acc1);
                float* H = Hf + g * NNODE * HSTR;
                #pragma unroll
                for (int r = 0; r < 4; ++r) {
                    H[(rbase + r) * HSTR + c0] = acc0[r] + bb0;
                    H[(rbase + r) * HSTR + c1] = acc1[r] + bb1;
                }
            }
        }
        __syncthreads();

        // ---- P7: pooled[g][l][d] = sum over nodes ----
        if (t < GPB * DIM) {
            const int g = t >> 6, d = t & 63;
            const float* H = Hf + g * NNODE * HSTR;
            float s = 0.f;
            #pragma unroll
            for (int n = 0; n < NNODE; ++n) s += H[n * HSTR + d];
            pooled[g][l * DIM + d] = s;
        }
    }
    __syncthreads();

    for (int i = t; i < GPB * CDIM; i += 256) {
        const int g = i / CDIM, d = i % CDIM;
        pooled_ws[((size_t)(b2 * GPB + g)) * CDIM + d] = pooled[g][d];
    }
}

// ---- classifier kernel: out = relu(pooled @ wc1 + bc1) @ wc2 + bc2 ----
extern "C" __global__ void __launch_bounds__(256)
classifier_kernel(const float* __restrict__ pooled_ws,
                  const unsigned short* __restrict__ wc1f,
                  const float* __restrict__ bc1, const float* __restrict__ wc2,
                  const float* __restrict__ bc2, float* __restrict__ out)
{
    #define PSTR 196
    __shared__ __align__(16) float P[16 * PSTR];
    __shared__ __align__(16) unsigned int afh[6 * 64 * 4];  // A-frags hi (s=0..5)
    __shared__ __align__(16) unsigned int afl[6 * 64 * 4];
    __shared__ float rsum[4][16];

    const int b = blockIdx.x;
    const int t = threadIdx.x;
    const int l = t & 63;
    const int w = t >> 6;
    const unsigned short* wc1lo = wc1f + 73728;

    // stage pooled rows (coalesced)
    for (int i = t; i < 16 * 48; i += 256) {
        const int row = i / 48, q = i % 48;
        const float4 v = ldg4(pooled_ws + ((size_t)(b * 16 + row)) * CDIM + q * 4);
        *reinterpret_cast<float4*>(&P[row * PSTR + q * 4]) = v;
    }
    __syncthreads();

    // build A-frags: entry e = s*64 + l holds P[row=l&15][k=s*32+(l>>4)*8+j]
    for (int e = t; e < 6 * 64; e += 256) {
        const int s = e >> 6, ll = e & 63;
        const int row = ll & 15;
        const int k0 = s * 32 + (ll >> 4) * 8;
        const float4 v0 = *reinterpret_cast<const float4*>(&P[row * PSTR + k0]);
        const float4 v1 = *reinterpret_cast<const float4*>(&P[row * PSTR + k0 + 4]);
        const float y[8] = { v0.x, v0.y, v0.z, v0.w, v1.x, v1.y, v1.z, v1.w };
        unsigned int uh[4], ul[4];
        #pragma unroll
        for (int j2 = 0; j2 < 4; ++j2) {
            uh[j2] = pk2(y[j2 * 2], y[j2 * 2 + 1]);
            ul[j2] = pk2lo(y[j2 * 2], y[j2 * 2 + 1], uh[j2]);
        }
        *reinterpret_cast<u32x4*>(&afh[e * 4]) = (u32x4){uh[0], uh[1], uh[2], uh[3]};
        *reinterpret_cast<u32x4*>(&afl[e * 4]) = (u32x4){ul[0], ul[1], ul[2], ul[3]};
    }
    __syncthreads();

    // wave w: n-tiles 6w .. 6w+5 (16 cols each)
    float part[4] = {0.f, 0.f, 0.f, 0.f};
    for (int nt = 0; nt < 6; ++nt) {
        const int n = w * 6 + nt;
        f32x4 acc = {0.f, 0.f, 0.f, 0.f};
        #pragma unroll
        for (int s = 0; s < 6; ++s) {
            const u32x4 ah = *(const u32x4*)&afh[(s * 64 + l) * 4];
            const u32x4 al = *(const u32x4*)&afl[(s * 64 + l) * 4];
            const u32x4 bh = *(const u32x4*)&wc1f [((s * 24 + n) * 64 + l) * 8];
            const u32x4 bl = *(const u32x4*)&wc1lo[((s * 24 + n) * 64 + l) * 8];
            acc = __builtin_amdgcn_mfma_f32_16x16x32_bf16(as_bf(ah), as_bf(bh), acc, 0, 0, 0);
            acc = __builtin_amdgcn_mfma_f32_16x16x32_bf16(as_bf(ah), as_bf(bl), acc, 0, 0, 0);
            acc = __builtin_amdgcn_mfma_f32_16x16x32_bf16(as_bf(al), as_bf(bh), acc, 0, 0, 0);
        }
        const int col = n * 16 + (l & 15);
        const float bias = bc1[col], w2 = wc2[col];
        #pragma unroll
        for (int r = 0; r < 4; ++r)
            part[r] += fmaxf(acc[r] + bias, 0.f) * w2;
    }
    // reduce over the 16 lanes (same rows, different cols)
    #pragma unroll
    for (int r = 0; r < 4; ++r) {
        part[r] += __shfl_xor(part[r], 1);
        part[r] += __shfl_xor(part[r], 2);
        part[r] += __shfl_xor(part[r], 4);
        part[r] += __shfl_xor(part[r], 8);
    }
    if ((l & 15) == 0) {
        const int g = l >> 4;
        #pragma unroll
        for (int r = 0; r < 4; ++r) rsum[w][g * 4 + r] = part[r];
    }
    __syncthreads();
    if (t < 16)
        out[b * 16 + t] = rsum[0][t] + rsum[1][t] + rsum[2][t] + rsum[3][t] + bc2[0];
}

extern "C" void kernel_launch(void* const* d_in, const int* in_sizes, int n_in,
                              void* d_out, int out_size, void* d_ws, size_t ws_size,
                              hipStream_t stream)
{
    const int*   x     = (const int*)d_in[0];
    const int*   los   = (const int*)d_in[1];
    const int*   eidx  = (const int*)d_in[2];
    const float* emb   = (const float*)d_in[3];
    const float* win1  = (const float*)d_in[4];
    const float* bin1  = (const float*)d_in[5];
    const float* gin_g = (const float*)d_in[6];
    const float* gin_b = (const float*)d_in[7];
    const float* win2  = (const float*)d_in[8];
    const float* bin2  = (const float*)d_in[9];
    const float* wh1   = (const float*)d_in[10];
    const float* bh1   = (const float*)d_in[11];
    const float* gh_g  = (const float*)d_in[12];
    const float* gh_b  = (const float*)d_in[13];
    const float* wh2   = (const float*)d_in[14];
    const float* bh2   = (const float*)d_in[15];
    const float* epsv  = (const float*)d_in[16];
    const float* wc1   = (const float*)d_in[17];
    const float* bc1   = (const float*)d_in[18];
    const float* wc2   = (const float*)d_in[19];
    const float* bc2   = (const float*)d_in[20];
    float* out = (float*)d_out;

    unsigned short* wsb      = (unsigned short*)((char*)d_ws + WS_WFRAG_OFF);
    unsigned short* wc1f     = (unsigned short*)((char*)d_ws + WS_WC1_OFF);
    float*          pooledws = (float*)((char*)d_ws + WS_POOL_OFF);

    hipLaunchKernelGGL(prep_w_kernel, dim3(16), dim3(256), 0, stream,
                       win1, win2, wh1, wh2, wc1, wsb, wc1f);
    hipLaunchKernelGGL(gin_fused_kernel, dim3(NBATCH / GPB), dim3(256), 0, stream,
                       x, los, eidx, emb, bin1, gin_g, gin_b, bin2,
                       bh1, gh_g, gh_b, bh2, epsv,
                       (const unsigned short*)wsb, pooledws);
    hipLaunchKernelGGL(classifier_kernel, dim3(NBATCH / 16), dim3(256), 0, stream,
                       (const float*)pooledws, (const unsigned short*)wc1f,
                       bc1, wc2, bc2, out);
}

// Round 7
// 62.368 us; speedup vs baseline: 6.6440x; 1.1843x over previous
//
#include <hip/hip_runtime.h>

#define NBATCH 4096
#define NNODE  32
#define NVOCAB 100
#define DIM    64
#define EPG    512
#define HSTR   68      // padded fp32 LDS row stride (272 B, 16B-aligned rows)
#define LN_EPS 1e-5f
#define CDIM   192     // 3*DIM
#define C2DIM  384     // classifier hidden

// workspace layout (bytes)
#define WS_WFRAG_OFF   0         // 4 x 16 KB  W-matrix frags
#define WS_WC1_OFF     65536     // wc1 frags: hi 147456 B + lo 147456 B
#define WS_POOL_OFF    360448    // pooled 4096*192 f32 = 3145728 B

typedef float          f32x4  __attribute__((ext_vector_type(4)));
typedef unsigned int   u32x4  __attribute__((ext_vector_type(4)));
typedef __bf16         bf16x8 __attribute__((ext_vector_type(8)));

__device__ __forceinline__ float4 ldg4(const float* __restrict__ p) {
    return *reinterpret_cast<const float4*>(p);
}
__device__ __forceinline__ unsigned short f2bf(float f) {           // native RNE cvt
    return __builtin_bit_cast(unsigned short, static_cast<__bf16>(f));
}
__device__ __forceinline__ float bf2f(unsigned short h) {
    return static_cast<float>(__builtin_bit_cast(__bf16, h));
}
__device__ __forceinline__ unsigned int pk2(float a, float b) {     // 2xbf16 pack
    return (unsigned int)f2bf(a) | ((unsigned int)f2bf(b) << 16);
}
__device__ __forceinline__ unsigned int pk2lo(float a, float b, unsigned int hi) {
    const float ra = a - bf2f((unsigned short)(hi & 0xffff));
    const float rb = b - bf2f((unsigned short)(hi >> 16));
    return pk2(ra, rb);
}
__device__ __forceinline__ bf16x8 as_bf(u32x4 v) {
    return __builtin_bit_cast(bf16x8, v);
}
#define MFMA(a, b, c) __builtin_amdgcn_mfma_f32_16x16x32_bf16(as_bf(a), as_bf(b), (c), 0, 0, 0)

// ---- pre-kernel: pack weights into bf16 hi/lo MFMA B-fragments ----
// blocks 0..3: win1,win2,wh1,wh2 (64x64). blocks 4..15: wc1 (192x384).
extern "C" __global__ void __launch_bounds__(256)
prep_w_kernel(const float* __restrict__ win1, const float* __restrict__ win2,
              const float* __restrict__ wh1,  const float* __restrict__ wh2,
              const float* __restrict__ wc1,
              unsigned short* __restrict__ wsb, unsigned short* __restrict__ wc1f)
{
    const int blk = blockIdx.x;
    if (blk < 4) {
        const float* Ws[4] = {win1, win2, wh1, wh2};
        const float* W = Ws[blk];
        unsigned short* hi = wsb + blk * 8192;
        unsigned short* lo = hi + 4096;
        for (int f = threadIdx.x; f < 512; f += 256) {
            const int s = f >> 8, n = (f >> 6) & 3, l = f & 63;
            const int g = l >> 4, c = l & 15, col = n * 16 + c;
            unsigned int uh[4], ul[4];
            #pragma unroll
            for (int j2 = 0; j2 < 4; ++j2) {
                const float a = W[(s * 32 + g * 8 + j2 * 2)     * DIM + col];
                const float b = W[(s * 32 + g * 8 + j2 * 2 + 1) * DIM + col];
                uh[j2] = pk2(a, b);
                ul[j2] = pk2lo(a, b, uh[j2]);
            }
            *(u32x4*)(hi + f * 8) = (u32x4){uh[0], uh[1], uh[2], uh[3]};
            *(u32x4*)(lo + f * 8) = (u32x4){ul[0], ul[1], ul[2], ul[3]};
        }
    } else {
        // wc1 frags: entry e = (s*24 + n)*64 + l holds wc1[k=s*32+(l>>4)*8+j][col=n*16+(l&15)]
        unsigned short* hi = wc1f;
        unsigned short* lo = wc1f + 6 * 24 * 64 * 8;   // 73728
        const int base = (blk - 4) * 768;
        for (int i = 0; i < 3; ++i) {
            const int e = base + i * 256 + threadIdx.x;
            const int s = e / (24 * 64), rem = e % (24 * 64);
            const int n = rem >> 6, l = rem & 63;
            const int col = n * 16 + (l & 15);
            const int k0 = s * 32 + (l >> 4) * 8;
            unsigned int uh[4], ul[4];
            #pragma unroll
            for (int j2 = 0; j2 < 4; ++j2) {
                const float a = wc1[(k0 + j2 * 2)     * C2DIM + col];
                const float b = wc1[(k0 + j2 * 2 + 1) * C2DIM + col];
                uh[j2] = pk2(a, b);
                ul[j2] = pk2lo(a, b, uh[j2]);
            }
            *(u32x4*)(hi + e * 8) = (u32x4){uh[0], uh[1], uh[2], uh[3]};
            *(u32x4*)(lo + e * 8) = (u32x4){ul[0], ul[1], ul[2], ul[3]};
        }
    }
}

// ==== main kernel: one WAVE = one graph; zero block barriers ====
extern "C" __global__ void __launch_bounds__(256, 4)
gin_fused_kernel(const int* __restrict__ x, const int* __restrict__ los,
                 const int* __restrict__ eidx,
                 const float* __restrict__ emb,
                 const float* __restrict__ bin1,
                 const float* __restrict__ gin_g, const float* __restrict__ gin_b,
                 const float* __restrict__ bin2,
                 const float* __restrict__ bh1,
                 const float* __restrict__ gh_g, const float* __restrict__ gh_b,
                 const float* __restrict__ bh2,
                 const float* __restrict__ epsv,
                 const unsigned short* __restrict__ wsb,
                 float* __restrict__ pooled_ws)
{
    __shared__ __align__(16) float S[4 * NNODE * HSTR];   // per-wave private 32x68 scratch

    const int t  = threadIdx.x;
    const int wv = t >> 6;
    const int l  = t & 63;
    const int b  = blockIdx.x * 4 + wv;
    float* scr = &S[wv * NNODE * HSTR];
    const int lc = l & 15;          // C-layout col-lane / frag row-lane
    const int lg = l >> 4;          // lane group

    // ---- histogram (wave-local; cnt aliases scratch rows 0..14) ----
    int* cnt = (int*)scr;
    #pragma unroll
    for (int i = 0; i < 16; ++i) cnt[l + 64 * i] = 0;
    {
        const int ebase = b * EPG;
        const int goff  = b * NNODE;
        #pragma unroll
        for (int i = 0; i < 8; ++i) {
            const int e = ebase + l + 64 * i;
            const int sN = eidx[e] - goff;
            const int dN = eidx[NBATCH * EPG + e] - goff;
            atomicAdd(&cnt[dN * NNODE + sN], 1);
        }
    }
    // ---- adjacency A-frags (hi only; counts exact in bf16) ----
    u32x4 adjf[2];
    #pragma unroll
    for (int m = 0; m < 2; ++m) {
        const int4 a0 = *(const int4*)&cnt[(m * 16 + lc) * NNODE + lg * 8];
        const int4 a1 = *(const int4*)&cnt[(m * 16 + lc) * NNODE + lg * 8 + 4];
        adjf[m] = (u32x4){ pk2((float)a0.x, (float)a0.y), pk2((float)a0.z, (float)a0.w),
                           pk2((float)a1.x, (float)a1.y), pk2((float)a1.z, (float)a1.w) };
    }
    // ---- embedding -> scratch (in-order LDS pipe: WAR vs cnt reads is safe) ----
    {
        const int node = l >> 1;
        const int idx = (node < NNODE - 1) ? x[b * (NNODE - 1) + node] : los[b];
        const float* er = emb + ((size_t)(node * NVOCAB + idx)) * DIM + (l & 1) * 32;
        float* sr = scr + node * HSTR + (l & 1) * 32;
        #pragma unroll
        for (int i = 0; i < 8; ++i)
            *reinterpret_cast<float4*>(sr + i * 4) = ldg4(er + i * 4);
    }

    f32x4 acc[2][4];                 // C-tiles: row = m*16+lg*4+r, col = n*16+lc
    u32x4 azh[2][2], azl[2][2];      // A-frags [m][s]

    for (int ly = 0; ly < 3; ++ly) {
        const float* B1 = ly ? bh1  : bin1;
        const float* Gg = ly ? gh_g : gin_g;
        const float* Gb = ly ? gh_b : gin_b;
        const float* B2 = ly ? bh2  : bin2;
        const unsigned short* W1f = wsb + (ly ? 2 : 0) * 8192;
        const unsigned short* W2f = wsb + (ly ? 3 : 1) * 8192;
        const float sc = 1.0f + epsv[ly];

        // ---- aggregation: z = sc*h + Aadj @ H  (seeds + B-frags from scratch) ----
        #pragma unroll
        for (int m = 0; m < 2; ++m)
            #pragma unroll
            for (int n = 0; n < 4; ++n)
                #pragma unroll
                for (int r = 0; r < 4; ++r)
                    acc[m][n][r] = sc * scr[(m * 16 + lg * 4 + r) * HSTR + n * 16 + lc];
        #pragma unroll
        for (int n = 0; n < 4; ++n) {
            float h[8];
            #pragma unroll
            for (int j = 0; j < 8; ++j) h[j] = scr[(lg * 8 + j) * HSTR + n * 16 + lc];
            u32x4 hh = (u32x4){ pk2(h[0],h[1]), pk2(h[2],h[3]), pk2(h[4],h[5]), pk2(h[6],h[7]) };
            u32x4 hl = (u32x4){ pk2lo(h[0],h[1],hh[0]), pk2lo(h[2],h[3],hh[1]),
                                pk2lo(h[4],h[5],hh[2]), pk2lo(h[6],h[7],hh[3]) };
            #pragma unroll
            for (int m = 0; m < 2; ++m) {
                acc[m][n] = MFMA(adjf[m], hh, acc[m][n]);
                acc[m][n] = MFMA(adjf[m], hl, acc[m][n]);
            }
        }

        // ---- z -> scratch; load A-frags; mm1 ----
        #pragma unroll
        for (int m = 0; m < 2; ++m)
            #pragma unroll
            for (int n = 0; n < 4; ++n)
                #pragma unroll
                for (int r = 0; r < 4; ++r)
                    scr[(m * 16 + lg * 4 + r) * HSTR + n * 16 + lc] = acc[m][n][r];
        #pragma unroll
        for (int m = 0; m < 2; ++m)
            #pragma unroll
            for (int s = 0; s < 2; ++s) {
                const float4 v0 = *(const float4*)&scr[(m * 16 + lc) * HSTR + s * 32 + lg * 8];
                const float4 v1 = *(const float4*)&scr[(m * 16 + lc) * HSTR + s * 32 + lg * 8 + 4];
                azh[m][s] = (u32x4){ pk2(v0.x,v0.y), pk2(v0.z,v0.w), pk2(v1.x,v1.y), pk2(v1.z,v1.w) };
                azl[m][s] = (u32x4){ pk2lo(v0.x,v0.y,azh[m][s][0]), pk2lo(v0.z,v0.w,azh[m][s][1]),
                                     pk2lo(v1.x,v1.y,azh[m][s][2]), pk2lo(v1.z,v1.w,azh[m][s][3]) };
            }
        #pragma unroll
        for (int m = 0; m < 2; ++m)
            #pragma unroll
            for (int n = 0; n < 4; ++n)
                acc[m][n] = (f32x4){0.f, 0.f, 0.f, 0.f};
        #pragma unroll
        for (int n = 0; n < 4; ++n)
            #pragma unroll
            for (int s = 0; s < 2; ++s) {
                const u32x4 wh = *(const u32x4*)(W1f +        ((s * 4 + n) * 64 + l) * 8);
                const u32x4 wl = *(const u32x4*)(W1f + 4096 + ((s * 4 + n) * 64 + l) * 8);
                #pragma unroll
                for (int m = 0; m < 2; ++m) {
                    acc[m][n] = MFMA(azh[m][s], wh, acc[m][n]);
                    acc[m][n] = MFMA(azh[m][s], wl, acc[m][n]);
                    acc[m][n] = MFMA(azl[m][s], wh, acc[m][n]);
                }
            }

        // ---- bias + LayerNorm + relu (in-register; rows live in 16 lanes) ----
        {
            float bv[4], gg[4], gb[4];
            #pragma unroll
            for (int n = 0; n < 4; ++n) { bv[n] = B1[n * 16 + lc]; gg[n] = Gg[n * 16 + lc]; gb[n] = Gb[n * 16 + lc]; }
            #pragma unroll
            for (int m = 0; m < 2; ++m)
                #pragma unroll
                for (int r = 0; r < 4; ++r) {
                    float a0 = acc[m][0][r] + bv[0], a1 = acc[m][1][r] + bv[1];
                    float a2 = acc[m][2][r] + bv[2], a3 = acc[m][3][r] + bv[3];
                    float s1 = a0 + a1 + a2 + a3;
                    float s2 = a0 * a0 + a1 * a1 + a2 * a2 + a3 * a3;
                    s1 += __shfl_xor(s1, 1); s1 += __shfl_xor(s1, 2);
                    s1 += __shfl_xor(s1, 4); s1 += __shfl_xor(s1, 8);
                    s2 += __shfl_xor(s2, 1); s2 += __shfl_xor(s2, 2);
                    s2 += __shfl_xor(s2, 4); s2 += __shfl_xor(s2, 8);
                    const float mu  = s1 * (1.0f / 64.0f);
                    const float var = s2 * (1.0f / 64.0f) - mu * mu;
                    const float inv = rsqrtf(var + LN_EPS);
                    acc[m][0][r] = fmaxf((a0 - mu) * inv * gg[0] + gb[0], 0.f);
                    acc[m][1][r] = fmaxf((a1 - mu) * inv * gg[1] + gb[1], 0.f);
                    acc[m][2][r] = fmaxf((a2 - mu) * inv * gg[2] + gb[2], 0.f);
                    acc[m][3][r] = fmaxf((a3 - mu) * inv * gg[3] + gb[3], 0.f);
                }
        }

        // ---- y -> scratch; load A-frags; mm2 ----
        #pragma unroll
        for (int m = 0; m < 2; ++m)
            #pragma unroll
            for (int n = 0; n < 4; ++n)
                #pragma unroll
                for (int r = 0; r < 4; ++r)
                    scr[(m * 16 + lg * 4 + r) * HSTR + n * 16 + lc] = acc[m][n][r];
        #pragma unroll
        for (int m = 0; m < 2; ++m)
            #pragma unroll
            for (int s = 0; s < 2; ++s) {
                const float4 v0 = *(const float4*)&scr[(m * 16 + lc) * HSTR + s * 32 + lg * 8];
                const float4 v1 = *(const float4*)&scr[(m * 16 + lc) * HSTR + s * 32 + lg * 8 + 4];
                azh[m][s] = (u32x4){ pk2(v0.x,v0.y), pk2(v0.z,v0.w), pk2(v1.x,v1.y), pk2(v1.z,v1.w) };
                azl[m][s] = (u32x4){ pk2lo(v0.x,v0.y,azh[m][s][0]), pk2lo(v0.z,v0.w,azh[m][s][1]),
                                     pk2lo(v1.x,v1.y,azh[m][s][2]), pk2lo(v1.z,v1.w,azh[m][s][3]) };
            }
        #pragma unroll
        for (int m = 0; m < 2; ++m)
            #pragma unroll
            for (int n = 0; n < 4; ++n)
                acc[m][n] = (f32x4){0.f, 0.f, 0.f, 0.f};
        #pragma unroll
        for (int n = 0; n < 4; ++n)
            #pragma unroll
            for (int s = 0; s < 2; ++s) {
                const u32x4 wh = *(const u32x4*)(W2f +        ((s * 4 + n) * 64 + l) * 8);
                const u32x4 wl = *(const u32x4*)(W2f + 4096 + ((s * 4 + n) * 64 + l) * 8);
                #pragma unroll
                for (int m = 0; m < 2; ++m) {
                    acc[m][n] = MFMA(azh[m][s], wh, acc[m][n]);
                    acc[m][n] = MFMA(azh[m][s], wl, acc[m][n]);
                    acc[m][n] = MFMA(azl[m][s], wh, acc[m][n]);
                }
            }
        // + bias2 -> layer output H
        #pragma unroll
        for (int n = 0; n < 4; ++n) {
            const float bb = B2[n * 16 + lc];
            #pragma unroll
            for (int m = 0; m < 2; ++m)
                #pragma unroll
                for (int r = 0; r < 4; ++r)
                    acc[m][n][r] += bb;
        }
        // H -> scratch (input to next layer's aggregation)
        #pragma unroll
        for (int m = 0; m < 2; ++m)
            #pragma unroll
            for (int n = 0; n < 4; ++n)
                #pragma unroll
                for (int r = 0; r < 4; ++r)
                    scr[(m * 16 + lg * 4 + r) * HSTR + n * 16 + lc] = acc[m][n][r];
        // ---- pooled[ly][col] = sum over 32 nodes ----
        #pragma unroll
        for (int n = 0; n < 4; ++n) {
            float p = 0.f;
            #pragma unroll
            for (int m = 0; m < 2; ++m)
                #pragma unroll
                for (int r = 0; r < 4; ++r) p += acc[m][n][r];
            p += __shfl_xor(p, 16);
            p += __shfl_xor(p, 32);
            if (l < 16)
                pooled_ws[(size_t)b * CDIM + ly * DIM + n * 16 + l] = p;
        }
    }
}

// ---- classifier kernel: out = relu(pooled @ wc1 + bc1) @ wc2 + bc2 ----
extern "C" __global__ void __launch_bounds__(256)
classifier_kernel(const float* __restrict__ pooled_ws,
                  const unsigned short* __restrict__ wc1f,
                  const float* __restrict__ bc1, const float* __restrict__ wc2,
                  const float* __restrict__ bc2, float* __restrict__ out)
{
    #define PSTR 196
    __shared__ __align__(16) float P[16 * PSTR];
    __shared__ __align__(16) unsigned int afh[6 * 64 * 4];  // A-frags hi (s=0..5)
    __shared__ __align__(16) unsigned int afl[6 * 64 * 4];
    __shared__ float rsum[4][16];

    const int b = blockIdx.x;
    const int t = threadIdx.x;
    const int l = t & 63;
    const int w = t >> 6;
    const unsigned short* wc1lo = wc1f + 73728;

    // stage pooled rows (coalesced)
    for (int i = t; i < 16 * 48; i += 256) {
        const int row = i / 48, q = i % 48;
        const float4 v = ldg4(pooled_ws + ((size_t)(b * 16 + row)) * CDIM + q * 4);
        *reinterpret_cast<float4*>(&P[row * PSTR + q * 4]) = v;
    }
    __syncthreads();

    // build A-frags: entry e = s*64 + l holds P[row=l&15][k=s*32+(l>>4)*8+j]
    for (int e = t; e < 6 * 64; e += 256) {
        const int s = e >> 6, ll = e & 63;
        const int row = ll & 15;
        const int k0 = s * 32 + (ll >> 4) * 8;
        const float4 v0 = *reinterpret_cast<const float4*>(&P[row * PSTR + k0]);
        const float4 v1 = *reinterpret_cast<const float4*>(&P[row * PSTR + k0 + 4]);
        const float y[8] = { v0.x, v0.y, v0.z, v0.w, v1.x, v1.y, v1.z, v1.w };
        unsigned int uh[4], ul[4];
        #pragma unroll
        for (int j2 = 0; j2 < 4; ++j2) {
            uh[j2] = pk2(y[j2 * 2], y[j2 * 2 + 1]);
            ul[j2] = pk2lo(y[j2 * 2], y[j2 * 2 + 1], uh[j2]);
        }
        *reinterpret_cast<u32x4*>(&afh[e * 4]) = (u32x4){uh[0], uh[1], uh[2], uh[3]};
        *reinterpret_cast<u32x4*>(&afl[e * 4]) = (u32x4){ul[0], ul[1], ul[2], ul[3]};
    }
    __syncthreads();

    // wave w: n-tiles 6w .. 6w+5 (16 cols each)
    float part[4] = {0.f, 0.f, 0.f, 0.f};
    for (int nt = 0; nt < 6; ++nt) {
        const int n = w * 6 + nt;
        f32x4 acc = {0.f, 0.f, 0.f, 0.f};
        #pragma unroll
        for (int s = 0; s < 6; ++s) {
            const u32x4 ah = *(const u32x4*)&afh[(s * 64 + l) * 4];
            const u32x4 al = *(const u32x4*)&afl[(s * 64 + l) * 4];
            const u32x4 bh = *(const u32x4*)&wc1f [((s * 24 + n) * 64 + l) * 8];
            const u32x4 bl = *(const u32x4*)&wc1lo[((s * 24 + n) * 64 + l) * 8];
            acc = MFMA(ah, bh, acc);
            acc = MFMA(ah, bl, acc);
            acc = MFMA(al, bh, acc);
        }
        const int col = n * 16 + (l & 15);
        const float bias = bc1[col], w2 = wc2[col];
        #pragma unroll
        for (int r = 0; r < 4; ++r)
            part[r] += fmaxf(acc[r] + bias, 0.f) * w2;
    }
    // reduce over the 16 lanes (same rows, different cols)
    #pragma unroll
    for (int r = 0; r < 4; ++r) {
        part[r] += __shfl_xor(part[r], 1);
        part[r] += __shfl_xor(part[r], 2);
        part[r] += __shfl_xor(part[r], 4);
        part[r] += __shfl_xor(part[r], 8);
    }
    if ((l & 15) == 0) {
        const int g = l >> 4;
        #pragma unroll
        for (int r = 0; r < 4; ++r) rsum[w][g * 4 + r] = part[r];
    }
    __syncthreads();
    if (t < 16)
        out[b * 16 + t] = rsum[0][t] + rsum[1][t] + rsum[2][t] + rsum[3][t] + bc2[0];
}

extern "C" void kernel_launch(void* const* d_in, const int* in_sizes, int n_in,
                              void* d_out, int out_size, void* d_ws, size_t ws_size,
                              hipStream_t stream)
{
    const int*   x     = (const int*)d_in[0];
    const int*   los   = (const int*)d_in[1];
    const int*   eidx  = (const int*)d_in[2];
    const float* emb   = (const float*)d_in[3];
    const float* win1  = (const float*)d_in[4];
    const float* bin1  = (const float*)d_in[5];
    const float* gin_g = (const float*)d_in[6];
    const float* gin_b = (const float*)d_in[7];
    const float* win2  = (const float*)d_in[8];
    const float* bin2  = (const float*)d_in[9];
    const float* wh1   = (const float*)d_in[10];
    const float* bh1   = (const float*)d_in[11];
    const float* gh_g  = (const float*)d_in[12];
    const float* gh_b  = (const float*)d_in[13];
    const float* wh2   = (const float*)d_in[14];
    const float* bh2   = (const float*)d_in[15];
    const float* epsv  = (const float*)d_in[16];
    const float* wc1   = (const float*)d_in[17];
    const float* bc1   = (const float*)d_in[18];
    const float* wc2   = (const float*)d_in[19];
    const float* bc2   = (const float*)d_in[20];
    float* out = (float*)d_out;

    unsigned short* wsb      = (unsigned short*)((char*)d_ws + WS_WFRAG_OFF);
    unsigned short* wc1f     = (unsigned short*)((char*)d_ws + WS_WC1_OFF);
    float*          pooledws = (float*)((char*)d_ws + WS_POOL_OFF);

    hipLaunchKernelGGL(prep_w_kernel, dim3(16), dim3(256), 0, stream,
                       win1, win2, wh1, wh2, wc1, wsb, wc1f);
    hipLaunchKernelGGL(gin_fused_kernel, dim3(NBATCH / 4), dim3(256), 0, stream,
                       x, los, eidx, emb, bin1, gin_g, gin_b, bin2,
                       bh1, gh_g, gh_b, bh2, epsv,
                       (const unsigned short*)wsb, pooledws);
    hipLaunchKernelGGL(classifier_kernel, dim3(NBATCH / 16), dim3(256), 0, stream,
                       (const float*)pooledws, (const unsigned short*)wc1f,
                       bc1, wc2, bc2, out);
}